// Round 5
// baseline (971.017 us; speedup 1.0000x reference)
//
#include <hip/hip_runtime.h>

#define NN      25000
#define TWO_N   50000
#define TT      8
#define CIN     32
#define ROWF    256      // TT*CIN floats per node row
#define COUT    64
#define FTOT    224
#define NEDGE   800000
#define SCAN_BS 1024
#define NBLK    ((TWO_N + SCAN_BS - 1) / SCAN_BS)   // 49

// ---- CSR build ----
__global__ void hist_kernel(const int* __restrict__ dst, int* __restrict__ counts) {
    int i = blockIdx.x * blockDim.x + threadIdx.x;
    if (i < NEDGE) atomicAdd(&counts[dst[i]], 1);
}

// Two-level scan: per-block exclusive scan + block sums
__global__ void scan1_kernel(const int* __restrict__ counts, int* __restrict__ row_ptr,
                             int* __restrict__ bsums) {
    __shared__ int lds[SCAN_BS];
    int i = blockIdx.x * SCAN_BS + (int)threadIdx.x;
    int v = (i < TWO_N) ? counts[i] : 0;
    lds[threadIdx.x] = v;
    __syncthreads();
    for (int off = 1; off < SCAN_BS; off <<= 1) {
        int t = ((int)threadIdx.x >= off) ? lds[threadIdx.x - off] : 0;
        __syncthreads();
        lds[threadIdx.x] += t;
        __syncthreads();
    }
    if (i < TWO_N) row_ptr[i] = lds[threadIdx.x] - v;   // block-local exclusive
    if (threadIdx.x == SCAN_BS - 1) bsums[blockIdx.x] = lds[SCAN_BS - 1];
}

__global__ void scan2_kernel(int* __restrict__ bsums, int* __restrict__ row_ptr) {
    int lane = threadIdx.x;                 // one wave
    int orig = (lane < NBLK) ? bsums[lane] : 0;
    int v = orig;
    for (int off = 1; off < 64; off <<= 1) {
        int t = __shfl_up(v, off);
        if (lane >= off) v += t;
    }
    if (lane < NBLK) bsums[lane] = v - orig;     // exclusive block offsets
    if (lane == NBLK - 1) row_ptr[TWO_N] = v;    // grand total
}

__global__ void scan3_kernel(int* __restrict__ row_ptr, const int* __restrict__ bsums) {
    int i = blockIdx.x * SCAN_BS + (int)threadIdx.x;
    if (i < TWO_N) row_ptr[i] += bsums[blockIdx.x];
}

__global__ void scatter_kernel(const int* __restrict__ src, const int* __restrict__ dst,
                               const float* __restrict__ ef, const int* __restrict__ row_ptr,
                               int* __restrict__ fill, int* __restrict__ ssrc,
                               float* __restrict__ sef) {
    int i = blockIdx.x * blockDim.x + threadIdx.x;
    if (i < NEDGE) {
        int d = dst[i];
        int p = row_ptr[d] + atomicAdd(&fill[d], 1);
        ssrc[p] = src[i];
        sef[p]  = ef[i];
    }
}

// ---- SpMM: one wave per dst node; out[node] = scale*sum(ef*hin[src]) - sub[node'] ----
__global__ __launch_bounds__(256) void spmm_kernel(
        const int* __restrict__ row_ptr, const int* __restrict__ ssrc,
        const float* __restrict__ sef,
        const float* __restrict__ hin, int wrap_in,
        const float* __restrict__ sub, int wrap_sub,
        float scale, float* __restrict__ out) {
    int wid  = (int)((blockIdx.x * blockDim.x + threadIdx.x) >> 6);
    int lane = threadIdx.x & 63;
    if (wid >= TWO_N) return;
    int beg = row_ptr[wid], end = row_ptr[wid + 1];
    float4 a0 = make_float4(0.f, 0.f, 0.f, 0.f);
    float4 a1 = a0, a2 = a0, a3 = a0;
    int e = beg;
    for (; e + 4 <= end; e += 4) {
        int s0 = ssrc[e], s1 = ssrc[e + 1], s2 = ssrc[e + 2], s3 = ssrc[e + 3];
        float w0 = sef[e], w1 = sef[e + 1], w2 = sef[e + 2], w3 = sef[e + 3];
        if (wrap_in) {
            if (s0 >= NN) s0 -= NN;
            if (s1 >= NN) s1 -= NN;
            if (s2 >= NN) s2 -= NN;
            if (s3 >= NN) s3 -= NN;
        }
        float4 v0 = ((const float4*)(hin + (size_t)s0 * ROWF))[lane];
        float4 v1 = ((const float4*)(hin + (size_t)s1 * ROWF))[lane];
        float4 v2 = ((const float4*)(hin + (size_t)s2 * ROWF))[lane];
        float4 v3 = ((const float4*)(hin + (size_t)s3 * ROWF))[lane];
        a0.x = fmaf(w0, v0.x, a0.x); a0.y = fmaf(w0, v0.y, a0.y);
        a0.z = fmaf(w0, v0.z, a0.z); a0.w = fmaf(w0, v0.w, a0.w);
        a1.x = fmaf(w1, v1.x, a1.x); a1.y = fmaf(w1, v1.y, a1.y);
        a1.z = fmaf(w1, v1.z, a1.z); a1.w = fmaf(w1, v1.w, a1.w);
        a2.x = fmaf(w2, v2.x, a2.x); a2.y = fmaf(w2, v2.y, a2.y);
        a2.z = fmaf(w2, v2.z, a2.z); a2.w = fmaf(w2, v2.w, a2.w);
        a3.x = fmaf(w3, v3.x, a3.x); a3.y = fmaf(w3, v3.y, a3.y);
        a3.z = fmaf(w3, v3.z, a3.z); a3.w = fmaf(w3, v3.w, a3.w);
    }
    for (; e < end; ++e) {
        int s = ssrc[e];
        float w = sef[e];
        if (wrap_in && s >= NN) s -= NN;
        float4 v = ((const float4*)(hin + (size_t)s * ROWF))[lane];
        a0.x = fmaf(w, v.x, a0.x); a0.y = fmaf(w, v.y, a0.y);
        a0.z = fmaf(w, v.z, a0.z); a0.w = fmaf(w, v.w, a0.w);
    }
    float4 acc;
    acc.x = (a0.x + a1.x) + (a2.x + a3.x);
    acc.y = (a0.y + a1.y) + (a2.y + a3.y);
    acc.z = (a0.z + a1.z) + (a2.z + a3.z);
    acc.w = (a0.w + a1.w) + (a2.w + a3.w);
    float4 r;
    if (sub != nullptr) {
        int sn = wid;
        if (wrap_sub && sn >= NN) sn -= NN;
        float4 sv = ((const float4*)(sub + (size_t)sn * ROWF))[lane];
        r.x = scale * acc.x - sv.x;
        r.y = scale * acc.y - sv.y;
        r.z = scale * acc.z - sv.z;
        r.w = scale * acc.w - sv.w;
    } else {
        r = acc;
    }
    ((float4*)(out + (size_t)wid * ROWF))[lane] = r;
}

__device__ __forceinline__ float rlane(float v, int idx) {
    return __int_as_float(__builtin_amdgcn_readlane(__float_as_int(v), idx));
}

// ---- Output matmul: one wave per NODE. h row is cooperatively loaded into the
// wave's VGPRs (lane L holds t=L>>3, f-quad L&7 of each of the 7 source arrays);
// broadcast to all lanes via v_readlane (VALU, zero LDS traffic). W in LDS as
// WT2[q][c] float4 (lane-contiguous b128, conflict-free, no pad): 56 reads/node.
// LDS = 57.3 KB -> 2 blocks/CU -> 16 waves/CU. VALU-bound: ~5.6k cyc/node.
__global__ __launch_bounds__(512, 4) void out_kernel(
        const float* __restrict__ feat, const float* __restrict__ X1,
        const float* __restrict__ X2, const float* __restrict__ X3,
        const float* __restrict__ W, const float* __restrict__ b,
        float* __restrict__ out) {
    __shared__ float4 WT2[(FTOT / 4) * COUT];   // [q][c], 57344 B
    for (int i = threadIdx.x; i < (FTOT / 4) * COUT; i += blockDim.x) {
        int q = i >> 6;          // f-quad 0..55
        int c = i & 63;          // col
        WT2[i] = make_float4(W[(4 * q + 0) * COUT + c], W[(4 * q + 1) * COUT + c],
                             W[(4 * q + 2) * COUT + c], W[(4 * q + 3) * COUT + c]);
    }
    __syncthreads();

    int lane = threadIdx.x & 63;
    int nwaves = (gridDim.x * blockDim.x) >> 6;
    int wid = (int)((blockIdx.x * blockDim.x + threadIdx.x) >> 6);
    float bias = b[lane];

    for (int node = wid; node < NN; node += nwaves) {
        size_t o_lo = (size_t)node * ROWF;
        size_t o_hi = (size_t)(node + NN) * ROWF;
        // cooperative coalesced load: one 1KB wave-load per source array
        float4 cur0 = ((const float4*)(feat + o_lo))[lane];
        float4 cur1 = ((const float4*)(X1 + o_lo))[lane];
        float4 cur2 = ((const float4*)(X1 + o_hi))[lane];
        float4 cur3 = ((const float4*)(X2 + o_lo))[lane];
        float4 cur4 = ((const float4*)(X2 + o_hi))[lane];
        float4 cur5 = ((const float4*)(X3 + o_lo))[lane];
        float4 cur6 = ((const float4*)(X3 + o_hi))[lane];

        float acc[TT];
        #pragma unroll
        for (int t = 0; t < TT; ++t) acc[t] = bias;

        #define DO_A(A, CUR)                                                   \
        for (int lf4 = 0; lf4 < 8; ++lf4) {                                    \
            float4 wv = WT2[((A * 8 + lf4) << 6) + lane];                      \
            _Pragma("unroll")                                                  \
            for (int t = 0; t < TT; ++t) {                                     \
                int idx = t * 8 + lf4;                                         \
                acc[t] = fmaf(rlane(CUR.x, idx), wv.x, acc[t]);                \
                acc[t] = fmaf(rlane(CUR.y, idx), wv.y, acc[t]);                \
                acc[t] = fmaf(rlane(CUR.z, idx), wv.z, acc[t]);                \
                acc[t] = fmaf(rlane(CUR.w, idx), wv.w, acc[t]);                \
            }                                                                  \
        }
        DO_A(0, cur0) DO_A(1, cur1) DO_A(2, cur2) DO_A(3, cur3)
        DO_A(4, cur4) DO_A(5, cur5) DO_A(6, cur6)
        #undef DO_A

        #pragma unroll
        for (int t = 0; t < TT; ++t)
            out[(size_t)node * (TT * COUT) + t * COUT + lane] = acc[t];
    }
}

extern "C" void kernel_launch(void* const* d_in, const int* in_sizes, int n_in,
                              void* d_out, int out_size, void* d_ws, size_t ws_size,
                              hipStream_t stream) {
    const float* feat = (const float*)d_in[0];
    const float* ef   = (const float*)d_in[1];
    const float* W    = (const float*)d_in[2];
    const float* b    = (const float*)d_in[3];
    const int*   src  = (const int*)d_in[4];
    const int*   dst  = (const int*)d_in[5];
    float* out = (float*)d_out;

    // Workspace layout (~160.5 MB)
    float* X1 = (float*)d_ws;
    float* X2 = X1 + (size_t)TWO_N * ROWF;
    float* X3 = X2 + (size_t)TWO_N * ROWF;
    int* row_ptr = (int*)(X3 + (size_t)TWO_N * ROWF);
    int* counts  = row_ptr + TWO_N + 64;
    int* ssrc    = counts  + TWO_N + 64;
    float* sef   = (float*)(ssrc + NEDGE);
    int* bsums   = (int*)(sef + NEDGE);

    // CSR build (by dst)
    hipMemsetAsync(counts, 0, TWO_N * sizeof(int), stream);
    hist_kernel<<<(NEDGE + 255) / 256, 256, 0, stream>>>(dst, counts);
    scan1_kernel<<<NBLK, SCAN_BS, 0, stream>>>(counts, row_ptr, bsums);
    scan2_kernel<<<1, 64, 0, stream>>>(bsums, row_ptr);
    scan3_kernel<<<NBLK, SCAN_BS, 0, stream>>>(row_ptr, bsums);
    hipMemsetAsync(counts, 0, TWO_N * sizeof(int), stream);
    scatter_kernel<<<(NEDGE + 255) / 256, 256, 0, stream>>>(src, dst, ef, row_ptr,
                                                            counts, ssrc, sef);

    // Chebyshev diffusion steps
    int spmm_grid = (TWO_N + 3) / 4;   // 4 waves per 256-thread block
    spmm_kernel<<<spmm_grid, 256, 0, stream>>>(row_ptr, ssrc, sef,
                                               feat, 1, nullptr, 0, 1.0f, X1);
    spmm_kernel<<<spmm_grid, 256, 0, stream>>>(row_ptr, ssrc, sef,
                                               X1, 0, feat, 1, 2.0f, X2);
    spmm_kernel<<<spmm_grid, 256, 0, stream>>>(row_ptr, ssrc, sef,
                                               X2, 0, X1, 0, 2.0f, X3);

    // Output projection: one node per wave; 512 blocks x 8 waves (2 blocks/CU)
    out_kernel<<<512, 512, 0, stream>>>(feat, X1, X2, X3, W, b, out);
}

// Round 6
// 747.781 us; speedup vs baseline: 1.2985x; 1.2985x over previous
//
#include <hip/hip_runtime.h>

#define NN      25000
#define TWO_N   50000
#define TT      8
#define CIN     32
#define ROWF    256      // TT*CIN floats per node row
#define COUT    64
#define FTOT    224
#define NEDGE   800000
#define SCAN_BS 1024
#define NBLK    ((TWO_N + SCAN_BS - 1) / SCAN_BS)   // 49

// ---- CSR build ----
__global__ void hist_kernel(const int* __restrict__ dst, int* __restrict__ counts) {
    int i = blockIdx.x * blockDim.x + threadIdx.x;
    if (i < NEDGE) atomicAdd(&counts[dst[i]], 1);
}

// Two-level scan: per-block exclusive scan + block sums
__global__ void scan1_kernel(const int* __restrict__ counts, int* __restrict__ row_ptr,
                             int* __restrict__ bsums) {
    __shared__ int lds[SCAN_BS];
    int i = blockIdx.x * SCAN_BS + (int)threadIdx.x;
    int v = (i < TWO_N) ? counts[i] : 0;
    lds[threadIdx.x] = v;
    __syncthreads();
    for (int off = 1; off < SCAN_BS; off <<= 1) {
        int t = ((int)threadIdx.x >= off) ? lds[threadIdx.x - off] : 0;
        __syncthreads();
        lds[threadIdx.x] += t;
        __syncthreads();
    }
    if (i < TWO_N) row_ptr[i] = lds[threadIdx.x] - v;   // block-local exclusive
    if (threadIdx.x == SCAN_BS - 1) bsums[blockIdx.x] = lds[SCAN_BS - 1];
}

__global__ void scan2_kernel(int* __restrict__ bsums, int* __restrict__ row_ptr) {
    int lane = threadIdx.x;                 // one wave
    int orig = (lane < NBLK) ? bsums[lane] : 0;
    int v = orig;
    for (int off = 1; off < 64; off <<= 1) {
        int t = __shfl_up(v, off);
        if (lane >= off) v += t;
    }
    if (lane < NBLK) bsums[lane] = v - orig;     // exclusive block offsets
    if (lane == NBLK - 1) row_ptr[TWO_N] = v;    // grand total
}

__global__ void scan3_kernel(int* __restrict__ row_ptr, const int* __restrict__ bsums) {
    int i = blockIdx.x * SCAN_BS + (int)threadIdx.x;
    if (i < TWO_N) row_ptr[i] += bsums[blockIdx.x];
}

__global__ void scatter_kernel(const int* __restrict__ src, const int* __restrict__ dst,
                               const float* __restrict__ ef, const int* __restrict__ row_ptr,
                               int* __restrict__ fill, int* __restrict__ ssrc,
                               float* __restrict__ sef) {
    int i = blockIdx.x * blockDim.x + threadIdx.x;
    if (i < NEDGE) {
        int d = dst[i];
        int p = row_ptr[d] + atomicAdd(&fill[d], 1);
        ssrc[p] = src[i];
        sef[p]  = ef[i];
    }
}

// ---- SpMM: one wave per dst node; out[node] = scale*sum(ef*hin[src]) - sub[node'] ----
__global__ __launch_bounds__(256) void spmm_kernel(
        const int* __restrict__ row_ptr, const int* __restrict__ ssrc,
        const float* __restrict__ sef,
        const float* __restrict__ hin, int wrap_in,
        const float* __restrict__ sub, int wrap_sub,
        float scale, float* __restrict__ out) {
    int wid  = (int)((blockIdx.x * blockDim.x + threadIdx.x) >> 6);
    int lane = threadIdx.x & 63;
    if (wid >= TWO_N) return;
    int beg = row_ptr[wid], end = row_ptr[wid + 1];
    float4 a0 = make_float4(0.f, 0.f, 0.f, 0.f);
    float4 a1 = a0, a2 = a0, a3 = a0;
    int e = beg;
    for (; e + 4 <= end; e += 4) {
        int s0 = ssrc[e], s1 = ssrc[e + 1], s2 = ssrc[e + 2], s3 = ssrc[e + 3];
        float w0 = sef[e], w1 = sef[e + 1], w2 = sef[e + 2], w3 = sef[e + 3];
        if (wrap_in) {
            if (s0 >= NN) s0 -= NN;
            if (s1 >= NN) s1 -= NN;
            if (s2 >= NN) s2 -= NN;
            if (s3 >= NN) s3 -= NN;
        }
        float4 v0 = ((const float4*)(hin + (size_t)s0 * ROWF))[lane];
        float4 v1 = ((const float4*)(hin + (size_t)s1 * ROWF))[lane];
        float4 v2 = ((const float4*)(hin + (size_t)s2 * ROWF))[lane];
        float4 v3 = ((const float4*)(hin + (size_t)s3 * ROWF))[lane];
        a0.x = fmaf(w0, v0.x, a0.x); a0.y = fmaf(w0, v0.y, a0.y);
        a0.z = fmaf(w0, v0.z, a0.z); a0.w = fmaf(w0, v0.w, a0.w);
        a1.x = fmaf(w1, v1.x, a1.x); a1.y = fmaf(w1, v1.y, a1.y);
        a1.z = fmaf(w1, v1.z, a1.z); a1.w = fmaf(w1, v1.w, a1.w);
        a2.x = fmaf(w2, v2.x, a2.x); a2.y = fmaf(w2, v2.y, a2.y);
        a2.z = fmaf(w2, v2.z, a2.z); a2.w = fmaf(w2, v2.w, a2.w);
        a3.x = fmaf(w3, v3.x, a3.x); a3.y = fmaf(w3, v3.y, a3.y);
        a3.z = fmaf(w3, v3.z, a3.z); a3.w = fmaf(w3, v3.w, a3.w);
    }
    for (; e < end; ++e) {
        int s = ssrc[e];
        float w = sef[e];
        if (wrap_in && s >= NN) s -= NN;
        float4 v = ((const float4*)(hin + (size_t)s * ROWF))[lane];
        a0.x = fmaf(w, v.x, a0.x); a0.y = fmaf(w, v.y, a0.y);
        a0.z = fmaf(w, v.z, a0.z); a0.w = fmaf(w, v.w, a0.w);
    }
    float4 acc;
    acc.x = (a0.x + a1.x) + (a2.x + a3.x);
    acc.y = (a0.y + a1.y) + (a2.y + a3.y);
    acc.z = (a0.z + a1.z) + (a2.z + a3.z);
    acc.w = (a0.w + a1.w) + (a2.w + a3.w);
    float4 r;
    if (sub != nullptr) {
        int sn = wid;
        if (wrap_sub && sn >= NN) sn -= NN;
        float4 sv = ((const float4*)(sub + (size_t)sn * ROWF))[lane];
        r.x = scale * acc.x - sv.x;
        r.y = scale * acc.y - sv.y;
        r.z = scale * acc.z - sv.z;
        r.w = scale * acc.w - sv.w;
    } else {
        r = acc;
    }
    ((float4*)(out + (size_t)wid * ROWF))[lane] = r;
}

__device__ __forceinline__ float rlane(float v, int idx) {
    return __int_as_float(__builtin_amdgcn_readlane(__float_as_int(v), idx));
}

// ---- Output matmul: one wave per NODE. h row cooperatively loaded into the
// wave's VGPRs (lane L holds t=L>>3, f-quad L&7 of each of the 7 source arrays);
// broadcast to all lanes via v_readlane (VALU, zero LDS traffic for h). W in LDS
// as WT2[q][c] float4 (lane-contiguous b128, conflict-free): 56 reads/node.
// __launch_bounds__(512, 2): hipcc 2nd arg = min BLOCKS/CU (CUDA semantics);
// 2 blocks/CU -> 128-VGPR cap, no spills (round 2/5: tighter bound -> 64 VGPR
// -> ~1GB scratch traffic; round 3 at (512,2): 128 VGPR, zero spills).
__global__ __launch_bounds__(512, 2) void out_kernel(
        const float* __restrict__ feat, const float* __restrict__ X1,
        const float* __restrict__ X2, const float* __restrict__ X3,
        const float* __restrict__ W, const float* __restrict__ b,
        float* __restrict__ out) {
    __shared__ float4 WT2[(FTOT / 4) * COUT];   // [q][c], 57344 B
    for (int i = threadIdx.x; i < (FTOT / 4) * COUT; i += blockDim.x) {
        int q = i >> 6;          // f-quad 0..55
        int c = i & 63;          // col
        WT2[i] = make_float4(W[(4 * q + 0) * COUT + c], W[(4 * q + 1) * COUT + c],
                             W[(4 * q + 2) * COUT + c], W[(4 * q + 3) * COUT + c]);
    }
    __syncthreads();

    int lane = threadIdx.x & 63;
    int nwaves = (gridDim.x * blockDim.x) >> 6;
    int wid = (int)((blockIdx.x * blockDim.x + threadIdx.x) >> 6);
    float bias = b[lane];

    for (int node = wid; node < NN; node += nwaves) {
        size_t o_lo = (size_t)node * ROWF;
        size_t o_hi = (size_t)(node + NN) * ROWF;
        // cooperative coalesced load: one 1KB wave-load per source array
        float4 cur0 = ((const float4*)(feat + o_lo))[lane];
        float4 cur1 = ((const float4*)(X1 + o_lo))[lane];
        float4 cur2 = ((const float4*)(X1 + o_hi))[lane];
        float4 cur3 = ((const float4*)(X2 + o_lo))[lane];
        float4 cur4 = ((const float4*)(X2 + o_hi))[lane];
        float4 cur5 = ((const float4*)(X3 + o_lo))[lane];
        float4 cur6 = ((const float4*)(X3 + o_hi))[lane];

        float acc[TT];
        #pragma unroll
        for (int t = 0; t < TT; ++t) acc[t] = bias;

        #define DO_A(A, CUR)                                                   \
        for (int lf4 = 0; lf4 < 8; ++lf4) {                                    \
            float4 wv = WT2[((A * 8 + lf4) << 6) + lane];                      \
            _Pragma("unroll")                                                  \
            for (int t = 0; t < TT; ++t) {                                     \
                int idx = t * 8 + lf4;                                         \
                acc[t] = fmaf(rlane(CUR.x, idx), wv.x, acc[t]);                \
                acc[t] = fmaf(rlane(CUR.y, idx), wv.y, acc[t]);                \
                acc[t] = fmaf(rlane(CUR.z, idx), wv.z, acc[t]);                \
                acc[t] = fmaf(rlane(CUR.w, idx), wv.w, acc[t]);                \
            }                                                                  \
        }
        DO_A(0, cur0) DO_A(1, cur1) DO_A(2, cur2) DO_A(3, cur3)
        DO_A(4, cur4) DO_A(5, cur5) DO_A(6, cur6)
        #undef DO_A

        #pragma unroll
        for (int t = 0; t < TT; ++t)
            out[(size_t)node * (TT * COUT) + t * COUT + lane] = acc[t];
    }
}

extern "C" void kernel_launch(void* const* d_in, const int* in_sizes, int n_in,
                              void* d_out, int out_size, void* d_ws, size_t ws_size,
                              hipStream_t stream) {
    const float* feat = (const float*)d_in[0];
    const float* ef   = (const float*)d_in[1];
    const float* W    = (const float*)d_in[2];
    const float* b    = (const float*)d_in[3];
    const int*   src  = (const int*)d_in[4];
    const int*   dst  = (const int*)d_in[5];
    float* out = (float*)d_out;

    // Workspace layout (~160.5 MB)
    float* X1 = (float*)d_ws;
    float* X2 = X1 + (size_t)TWO_N * ROWF;
    float* X3 = X2 + (size_t)TWO_N * ROWF;
    int* row_ptr = (int*)(X3 + (size_t)TWO_N * ROWF);
    int* counts  = row_ptr + TWO_N + 64;
    int* ssrc    = counts  + TWO_N + 64;
    float* sef   = (float*)(ssrc + NEDGE);
    int* bsums   = (int*)(sef + NEDGE);

    // CSR build (by dst)
    hipMemsetAsync(counts, 0, TWO_N * sizeof(int), stream);
    hist_kernel<<<(NEDGE + 255) / 256, 256, 0, stream>>>(dst, counts);
    scan1_kernel<<<NBLK, SCAN_BS, 0, stream>>>(counts, row_ptr, bsums);
    scan2_kernel<<<1, 64, 0, stream>>>(bsums, row_ptr);
    scan3_kernel<<<NBLK, SCAN_BS, 0, stream>>>(row_ptr, bsums);
    hipMemsetAsync(counts, 0, TWO_N * sizeof(int), stream);
    scatter_kernel<<<(NEDGE + 255) / 256, 256, 0, stream>>>(src, dst, ef, row_ptr,
                                                            counts, ssrc, sef);

    // Chebyshev diffusion steps
    int spmm_grid = (TWO_N + 3) / 4;   // 4 waves per 256-thread block
    spmm_kernel<<<spmm_grid, 256, 0, stream>>>(row_ptr, ssrc, sef,
                                               feat, 1, nullptr, 0, 1.0f, X1);
    spmm_kernel<<<spmm_grid, 256, 0, stream>>>(row_ptr, ssrc, sef,
                                               X1, 0, feat, 1, 2.0f, X2);
    spmm_kernel<<<spmm_grid, 256, 0, stream>>>(row_ptr, ssrc, sef,
                                               X2, 0, X1, 0, 2.0f, X3);

    // Output projection: one node per wave; 512 blocks x 8 waves (2 blocks/CU)
    out_kernel<<<512, 512, 0, stream>>>(feat, X1, X2, X3, W, b, out);
}

// Round 7
// 632.901 us; speedup vs baseline: 1.5342x; 1.1815x over previous
//
#include <hip/hip_runtime.h>

#define NN      25000
#define TWO_N   50000
#define TT      8
#define CIN     32
#define ROWF    256      // TT*CIN floats per node row
#define COUT    64
#define FTOT    224
#define NEDGE   800000
#define NROWS   (NN * TT)          // 200000 output rows
#define SCAN_BS 1024
#define NBLK    ((TWO_N + SCAN_BS - 1) / SCAN_BS)   // 49

// ---- CSR build ----
__global__ void hist_kernel(const int* __restrict__ dst, int* __restrict__ counts) {
    int i = blockIdx.x * blockDim.x + threadIdx.x;
    if (i < NEDGE) atomicAdd(&counts[dst[i]], 1);
}

// Two-level scan: per-block exclusive scan + block sums
__global__ void scan1_kernel(const int* __restrict__ counts, int* __restrict__ row_ptr,
                             int* __restrict__ bsums) {
    __shared__ int lds[SCAN_BS];
    int i = blockIdx.x * SCAN_BS + (int)threadIdx.x;
    int v = (i < TWO_N) ? counts[i] : 0;
    lds[threadIdx.x] = v;
    __syncthreads();
    for (int off = 1; off < SCAN_BS; off <<= 1) {
        int t = ((int)threadIdx.x >= off) ? lds[threadIdx.x - off] : 0;
        __syncthreads();
        lds[threadIdx.x] += t;
        __syncthreads();
    }
    if (i < TWO_N) row_ptr[i] = lds[threadIdx.x] - v;   // block-local exclusive
    if (threadIdx.x == SCAN_BS - 1) bsums[blockIdx.x] = lds[SCAN_BS - 1];
}

__global__ void scan2_kernel(int* __restrict__ bsums, int* __restrict__ row_ptr) {
    int lane = threadIdx.x;                 // one wave
    int orig = (lane < NBLK) ? bsums[lane] : 0;
    int v = orig;
    for (int off = 1; off < 64; off <<= 1) {
        int t = __shfl_up(v, off);
        if (lane >= off) v += t;
    }
    if (lane < NBLK) bsums[lane] = v - orig;     // exclusive block offsets
    if (lane == NBLK - 1) row_ptr[TWO_N] = v;    // grand total
}

__global__ void scan3_kernel(int* __restrict__ row_ptr, const int* __restrict__ bsums) {
    int i = blockIdx.x * SCAN_BS + (int)threadIdx.x;
    if (i < TWO_N) row_ptr[i] += bsums[blockIdx.x];
}

__global__ void scatter_kernel(const int* __restrict__ src, const int* __restrict__ dst,
                               const float* __restrict__ ef, const int* __restrict__ row_ptr,
                               int* __restrict__ fill, int* __restrict__ ssrc,
                               float* __restrict__ sef) {
    int i = blockIdx.x * blockDim.x + threadIdx.x;
    if (i < NEDGE) {
        int d = dst[i];
        int p = row_ptr[d] + atomicAdd(&fill[d], 1);
        ssrc[p] = src[i];
        sef[p]  = ef[i];
    }
}

// feat -> workspace slot 0 (so all 7 h-segments sit at base + a*(NN*ROWF) + r*32)
__global__ void copy_feat_kernel(const float* __restrict__ feat, float* __restrict__ dstp) {
    int i = blockIdx.x * blockDim.x + threadIdx.x;
    ((float4*)dstp)[i] = ((const float4*)feat)[i];
}

// ---- SpMM: one wave per dst node; out[node] = scale*sum(ef*hin[src]) - sub[node'] ----
__global__ __launch_bounds__(256) void spmm_kernel(
        const int* __restrict__ row_ptr, const int* __restrict__ ssrc,
        const float* __restrict__ sef,
        const float* __restrict__ hin, int wrap_in,
        const float* __restrict__ sub, int wrap_sub,
        float scale, float* __restrict__ out) {
    int wid  = (int)((blockIdx.x * blockDim.x + threadIdx.x) >> 6);
    int lane = threadIdx.x & 63;
    if (wid >= TWO_N) return;
    int beg = row_ptr[wid], end = row_ptr[wid + 1];
    float4 a0 = make_float4(0.f, 0.f, 0.f, 0.f);
    float4 a1 = a0, a2 = a0, a3 = a0;
    int e = beg;
    for (; e + 4 <= end; e += 4) {
        int s0 = ssrc[e], s1 = ssrc[e + 1], s2 = ssrc[e + 2], s3 = ssrc[e + 3];
        float w0 = sef[e], w1 = sef[e + 1], w2 = sef[e + 2], w3 = sef[e + 3];
        if (wrap_in) {
            if (s0 >= NN) s0 -= NN;
            if (s1 >= NN) s1 -= NN;
            if (s2 >= NN) s2 -= NN;
            if (s3 >= NN) s3 -= NN;
        }
        float4 v0 = ((const float4*)(hin + (size_t)s0 * ROWF))[lane];
        float4 v1 = ((const float4*)(hin + (size_t)s1 * ROWF))[lane];
        float4 v2 = ((const float4*)(hin + (size_t)s2 * ROWF))[lane];
        float4 v3 = ((const float4*)(hin + (size_t)s3 * ROWF))[lane];
        a0.x = fmaf(w0, v0.x, a0.x); a0.y = fmaf(w0, v0.y, a0.y);
        a0.z = fmaf(w0, v0.z, a0.z); a0.w = fmaf(w0, v0.w, a0.w);
        a1.x = fmaf(w1, v1.x, a1.x); a1.y = fmaf(w1, v1.y, a1.y);
        a1.z = fmaf(w1, v1.z, a1.z); a1.w = fmaf(w1, v1.w, a1.w);
        a2.x = fmaf(w2, v2.x, a2.x); a2.y = fmaf(w2, v2.y, a2.y);
        a2.z = fmaf(w2, v2.z, a2.z); a2.w = fmaf(w2, v2.w, a2.w);
        a3.x = fmaf(w3, v3.x, a3.x); a3.y = fmaf(w3, v3.y, a3.y);
        a3.z = fmaf(w3, v3.z, a3.z); a3.w = fmaf(w3, v3.w, a3.w);
    }
    for (; e < end; ++e) {
        int s = ssrc[e];
        float w = sef[e];
        if (wrap_in && s >= NN) s -= NN;
        float4 v = ((const float4*)(hin + (size_t)s * ROWF))[lane];
        a0.x = fmaf(w, v.x, a0.x); a0.y = fmaf(w, v.y, a0.y);
        a0.z = fmaf(w, v.z, a0.z); a0.w = fmaf(w, v.w, a0.w);
    }
    float4 acc;
    acc.x = (a0.x + a1.x) + (a2.x + a3.x);
    acc.y = (a0.y + a1.y) + (a2.y + a3.y);
    acc.z = (a0.z + a1.z) + (a2.z + a3.z);
    acc.w = (a0.w + a1.w) + (a2.w + a3.w);
    float4 r;
    if (sub != nullptr) {
        int sn = wid;
        if (wrap_sub && sn >= NN) sn -= NN;
        float4 sv = ((const float4*)(sub + (size_t)sn * ROWF))[lane];
        r.x = scale * acc.x - sv.x;
        r.y = scale * acc.y - sv.y;
        r.z = scale * acc.z - sv.z;
        r.w = scale * acc.w - sv.w;
    } else {
        r = acc;
    }
    ((float4*)(out + (size_t)wid * ROWF))[lane] = r;
}

// ---- Output matmul: THREAD-PER-ROW, W via scalar pipe.
// Each thread owns one (node,t) row: acc[64] in VGPRs, h row = 7 contiguous
// 32-float segments at H + a*(NN*ROWF) + r*32 (feat copied into slot 0).
// W index (wp uniform + literal) -> s_load; FMA = v_fmac_f32 vacc, s_w, v_h
// (VOP2, no broadcast cost). a-loop rolled: I$ body ~10KB. ~110 VGPR, no LDS.
__global__ __launch_bounds__(256) void out_kernel(
        const float* __restrict__ H, const float* __restrict__ W,
        const float* __restrict__ b, float* __restrict__ out) {
    int r = blockIdx.x * blockDim.x + threadIdx.x;
    if (r >= NROWS) return;

    float acc[COUT];
    #pragma unroll
    for (int c = 0; c < COUT; ++c) acc[c] = b[c];   // uniform -> s_load

    const float4* hp = (const float4*)(H + (size_t)r * CIN);
    const float*  wp = W;
    for (int a = 0; a < 7; ++a) {
        float hh[CIN];
        #pragma unroll
        for (int q = 0; q < 8; ++q) {
            float4 v = hp[q];
            hh[q * 4 + 0] = v.x; hh[q * 4 + 1] = v.y;
            hh[q * 4 + 2] = v.z; hh[q * 4 + 3] = v.w;
        }
        #pragma unroll
        for (int j = 0; j < CIN; ++j) {
            #pragma unroll
            for (int c = 0; c < COUT; ++c)
                acc[c] = fmaf(hh[j], wp[j * COUT + c], acc[c]);   // s_w * v_h
        }
        hp += (size_t)NN * ROWF / 4;   // next h-segment (stride NN*ROWF floats)
        wp += CIN * COUT;              // next 32 W rows
    }

    float4* op = (float4*)(out + (size_t)r * COUT);
    #pragma unroll
    for (int q = 0; q < COUT / 4; ++q)
        op[q] = make_float4(acc[4 * q], acc[4 * q + 1], acc[4 * q + 2], acc[4 * q + 3]);
}

extern "C" void kernel_launch(void* const* d_in, const int* in_sizes, int n_in,
                              void* d_out, int out_size, void* d_ws, size_t ws_size,
                              hipStream_t stream) {
    const float* feat = (const float*)d_in[0];
    const float* ef   = (const float*)d_in[1];
    const float* W    = (const float*)d_in[2];
    const float* b    = (const float*)d_in[3];
    const int*   src  = (const int*)d_in[4];
    const int*   dst  = (const int*)d_in[5];
    float* out = (float*)d_out;

    // Workspace layout (~187 MB):
    // [FEATC NN*256][X1 2N*256][X2 2N*256][X3 2N*256][ints...]
    float* FEATC = (float*)d_ws;
    float* X1 = FEATC + (size_t)NN * ROWF;
    float* X2 = X1 + (size_t)TWO_N * ROWF;
    float* X3 = X2 + (size_t)TWO_N * ROWF;
    int* row_ptr = (int*)(X3 + (size_t)TWO_N * ROWF);
    int* counts  = row_ptr + TWO_N + 64;
    int* ssrc    = counts  + TWO_N + 64;
    float* sef   = (float*)(ssrc + NEDGE);
    int* bsums   = (int*)(sef + NEDGE);

    // feat -> slot 0 (independent of CSR; kick off first)
    copy_feat_kernel<<<(NN * ROWF / 4) / 256, 256, 0, stream>>>(feat, FEATC);

    // CSR build (by dst)
    hipMemsetAsync(counts, 0, TWO_N * sizeof(int), stream);
    hist_kernel<<<(NEDGE + 255) / 256, 256, 0, stream>>>(dst, counts);
    scan1_kernel<<<NBLK, SCAN_BS, 0, stream>>>(counts, row_ptr, bsums);
    scan2_kernel<<<1, 64, 0, stream>>>(bsums, row_ptr);
    scan3_kernel<<<NBLK, SCAN_BS, 0, stream>>>(row_ptr, bsums);
    hipMemsetAsync(counts, 0, TWO_N * sizeof(int), stream);
    scatter_kernel<<<(NEDGE + 255) / 256, 256, 0, stream>>>(src, dst, ef, row_ptr,
                                                            counts, ssrc, sef);

    // Chebyshev diffusion steps
    int spmm_grid = (TWO_N + 3) / 4;   // 4 waves per 256-thread block
    spmm_kernel<<<spmm_grid, 256, 0, stream>>>(row_ptr, ssrc, sef,
                                               feat, 1, nullptr, 0, 1.0f, X1);
    spmm_kernel<<<spmm_grid, 256, 0, stream>>>(row_ptr, ssrc, sef,
                                               X1, 0, feat, 1, 2.0f, X2);
    spmm_kernel<<<spmm_grid, 256, 0, stream>>>(row_ptr, ssrc, sef,
                                               X2, 0, X1, 0, 2.0f, X3);

    // Output projection: thread-per-row
    out_kernel<<<(NROWS + 255) / 256, 256, 0, stream>>>(FEATC, W, b, out);
}

// Round 9
// 566.378 us; speedup vs baseline: 1.7144x; 1.1175x over previous
//
#include <hip/hip_runtime.h>

#define NN      25000
#define TWO_N   50000
#define TT      8
#define CIN     32
#define ROWF    256      // TT*CIN floats per node row
#define COUT    64
#define FTOT    224
#define NEDGE   800000
#define NROWS   (NN * TT)          // 200000 output rows
#define SEG     ((size_t)NN * ROWF)  // floats per h-segment (200000 rows x 32)
#define SCAN_BS 1024
#define NBLK    ((TWO_N + SCAN_BS - 1) / SCAN_BS)   // 49

// out_gemm tiling
#define BM       256
#define BK       32
#define HS_PITCH 256   // k-major [32][256]; reads = 8 unique addrs/wave, 2-way max
#define WS_PITCH 64    // k-major [32][64]; same pattern

// ---- CSR build ----
__global__ void hist_kernel(const int* __restrict__ dst, int* __restrict__ counts) {
    int i = blockIdx.x * blockDim.x + threadIdx.x;
    if (i < NEDGE) atomicAdd(&counts[dst[i]], 1);
}

__global__ void scan1_kernel(const int* __restrict__ counts, int* __restrict__ row_ptr,
                             int* __restrict__ bsums) {
    __shared__ int lds[SCAN_BS];
    int i = blockIdx.x * SCAN_BS + (int)threadIdx.x;
    int v = (i < TWO_N) ? counts[i] : 0;
    lds[threadIdx.x] = v;
    __syncthreads();
    for (int off = 1; off < SCAN_BS; off <<= 1) {
        int t = ((int)threadIdx.x >= off) ? lds[threadIdx.x - off] : 0;
        __syncthreads();
        lds[threadIdx.x] += t;
        __syncthreads();
    }
    if (i < TWO_N) row_ptr[i] = lds[threadIdx.x] - v;
    if (threadIdx.x == SCAN_BS - 1) bsums[blockIdx.x] = lds[SCAN_BS - 1];
}

__global__ void scan2_kernel(int* __restrict__ bsums, int* __restrict__ row_ptr) {
    int lane = threadIdx.x;
    int orig = (lane < NBLK) ? bsums[lane] : 0;
    int v = orig;
    for (int off = 1; off < 64; off <<= 1) {
        int t = __shfl_up(v, off);
        if (lane >= off) v += t;
    }
    if (lane < NBLK) bsums[lane] = v - orig;
    if (lane == NBLK - 1) row_ptr[TWO_N] = v;
}

__global__ void scan3_kernel(int* __restrict__ row_ptr, const int* __restrict__ bsums) {
    int i = blockIdx.x * SCAN_BS + (int)threadIdx.x;
    if (i < TWO_N) row_ptr[i] += bsums[blockIdx.x];
}

__global__ void scatter_kernel(const int* __restrict__ src, const int* __restrict__ dst,
                               const float* __restrict__ ef, const int* __restrict__ row_ptr,
                               int* __restrict__ fill, int* __restrict__ ssrc,
                               float* __restrict__ sef) {
    int i = blockIdx.x * blockDim.x + threadIdx.x;
    if (i < NEDGE) {
        int d = dst[i];
        int p = row_ptr[d] + atomicAdd(&fill[d], 1);
        ssrc[p] = src[i];
        sef[p]  = ef[i];
    }
}

// feat -> workspace slot 0 (so all 7 h-segments sit at H + a*SEG + r*32)
__global__ void copy_feat_kernel(const float* __restrict__ feat, float* __restrict__ dstp) {
    int i = blockIdx.x * blockDim.x + threadIdx.x;
    ((float4*)dstp)[i] = ((const float4*)feat)[i];
}

// ---- SpMM: one wave per dst node; out[node] = scale*sum(ef*hin[src]) - sub[node'] ----
__global__ __launch_bounds__(256) void spmm_kernel(
        const int* __restrict__ row_ptr, const int* __restrict__ ssrc,
        const float* __restrict__ sef,
        const float* __restrict__ hin, int wrap_in,
        const float* __restrict__ sub, int wrap_sub,
        float scale, float* __restrict__ out) {
    int wid  = (int)((blockIdx.x * blockDim.x + threadIdx.x) >> 6);
    int lane = threadIdx.x & 63;
    if (wid >= TWO_N) return;
    int beg = row_ptr[wid], end = row_ptr[wid + 1];
    float4 a0 = make_float4(0.f, 0.f, 0.f, 0.f);
    float4 a1 = a0, a2 = a0, a3 = a0;
    int e = beg;
    for (; e + 4 <= end; e += 4) {
        int s0 = ssrc[e], s1 = ssrc[e + 1], s2 = ssrc[e + 2], s3 = ssrc[e + 3];
        float w0 = sef[e], w1 = sef[e + 1], w2 = sef[e + 2], w3 = sef[e + 3];
        if (wrap_in) {
            if (s0 >= NN) s0 -= NN;
            if (s1 >= NN) s1 -= NN;
            if (s2 >= NN) s2 -= NN;
            if (s3 >= NN) s3 -= NN;
        }
        float4 v0 = ((const float4*)(hin + (size_t)s0 * ROWF))[lane];
        float4 v1 = ((const float4*)(hin + (size_t)s1 * ROWF))[lane];
        float4 v2 = ((const float4*)(hin + (size_t)s2 * ROWF))[lane];
        float4 v3 = ((const float4*)(hin + (size_t)s3 * ROWF))[lane];
        a0.x = fmaf(w0, v0.x, a0.x); a0.y = fmaf(w0, v0.y, a0.y);
        a0.z = fmaf(w0, v0.z, a0.z); a0.w = fmaf(w0, v0.w, a0.w);
        a1.x = fmaf(w1, v1.x, a1.x); a1.y = fmaf(w1, v1.y, a1.y);
        a1.z = fmaf(w1, v1.z, a1.z); a1.w = fmaf(w1, v1.w, a1.w);
        a2.x = fmaf(w2, v2.x, a2.x); a2.y = fmaf(w2, v2.y, a2.y);
        a2.z = fmaf(w2, v2.z, a2.z); a2.w = fmaf(w2, v2.w, a2.w);
        a3.x = fmaf(w3, v3.x, a3.x); a3.y = fmaf(w3, v3.y, a3.y);
        a3.z = fmaf(w3, v3.z, a3.z); a3.w = fmaf(w3, v3.w, a3.w);
    }
    for (; e < end; ++e) {
        int s = ssrc[e];
        float w = sef[e];
        if (wrap_in && s >= NN) s -= NN;
        float4 v = ((const float4*)(hin + (size_t)s * ROWF))[lane];
        a0.x = fmaf(w, v.x, a0.x); a0.y = fmaf(w, v.y, a0.y);
        a0.z = fmaf(w, v.z, a0.z); a0.w = fmaf(w, v.w, a0.w);
    }
    float4 acc;
    acc.x = (a0.x + a1.x) + (a2.x + a3.x);
    acc.y = (a0.y + a1.y) + (a2.y + a3.y);
    acc.z = (a0.z + a1.z) + (a2.z + a3.z);
    acc.w = (a0.w + a1.w) + (a2.w + a3.w);
    float4 r;
    if (sub != nullptr) {
        int sn = wid;
        if (wrap_sub && sn >= NN) sn -= NN;
        float4 sv = ((const float4*)(sub + (size_t)sn * ROWF))[lane];
        r.x = scale * acc.x - sv.x;
        r.y = scale * acc.y - sv.y;
        r.z = scale * acc.z - sv.z;
        r.w = scale * acc.w - sv.w;
    } else {
        r = acc;
    }
    ((float4*)(out + (size_t)wid * ROWF))[lane] = r;
}

// ---- Output matmul: classic register-tiled GEMM.
// Block 256 thr = 256 rows x 64 cols; thread tile 8x8 (acc 64 VGPR).
// K = 7 steps of BK=32 (one h-segment; staging read = contiguous 32KB, coalesced).
// Hs k-major [32][256], Ws [32][64], NO swizzle: a wave's compute read has only
// 8 unique addresses (8-lane broadcast each), 8 banks apart -> worst 2-way
// conflict (free, m136). Round-8 swizzle was non-injective (rows 60..67 collided)
// -> correctness failure. Staging writes ~8-way conflicted but 32KB/step = noise.
__global__ __launch_bounds__(256, 2) void out_gemm_kernel(
        const float* __restrict__ H, const float* __restrict__ W,
        const float* __restrict__ b, float* __restrict__ out) {
    __shared__ float Hs[BK * HS_PITCH];   // 32768 B
    __shared__ float Ws[BK * WS_PITCH];   //  8192 B  (40 KB total -> 3 blocks/CU)
    int tid = threadIdx.x;
    int rbase = blockIdx.x * BM;
    int rg = tid >> 3;          // row group 0..31 (8 rows each)
    int cg = tid & 7;           // col group 0..7  (8 cols each)

    float acc[8][8];
    {
        float4 b0 = ((const float4*)b)[cg * 2];
        float4 b1 = ((const float4*)b)[cg * 2 + 1];
        #pragma unroll
        for (int i = 0; i < 8; ++i) {
            acc[i][0] = b0.x; acc[i][1] = b0.y; acc[i][2] = b0.z; acc[i][3] = b0.w;
            acc[i][4] = b1.x; acc[i][5] = b1.y; acc[i][6] = b1.z; acc[i][7] = b1.w;
        }
    }

    int hbase4 = rg * 2;   // float4 idx of this thread's 8 rows within a k-row
    int wbase4 = cg * 2;

    #pragma unroll 1
    for (int a = 0; a < 7; ++a) {
        // ---- stage H tile: rows rbase..rbase+255, one 32-float segment each ----
        const float4* Hseg = (const float4*)(H + (size_t)a * SEG + (size_t)rbase * CIN);
        #pragma unroll
        for (int j = 0; j < 8; ++j) {
            int f = j * 256 + tid;            // float4 index 0..2047 (row-major [r][q])
            int r = f >> 3, q = f & 7;
            float4 v = Hseg[f];
            Hs[(4 * q + 0) * HS_PITCH + r] = v.x;
            Hs[(4 * q + 1) * HS_PITCH + r] = v.y;
            Hs[(4 * q + 2) * HS_PITCH + r] = v.z;
            Hs[(4 * q + 3) * HS_PITCH + r] = v.w;
        }
        // ---- stage W tile: [32][64], already k-major in global ----
        const float4* W4 = (const float4*)(W + (size_t)a * CIN * COUT);
        #pragma unroll
        for (int j = 0; j < 2; ++j) {
            int f = j * 256 + tid;            // 0..511 = [k][cq]
            int k = f >> 4, cq = f & 15;
            ((float4*)&Ws[k * WS_PITCH])[cq] = W4[f];
        }
        __syncthreads();

        // ---- compute ----
        #pragma unroll 4
        for (int k = 0; k < BK; ++k) {
            const float4* hk = (const float4*)&Hs[k * HS_PITCH];
            const float4* wk = (const float4*)&Ws[k * WS_PITCH];
            float4 h0 = hk[hbase4], h1 = hk[hbase4 + 1];
            float4 w0 = wk[wbase4], w1 = wk[wbase4 + 1];
            float hh[8] = {h0.x, h0.y, h0.z, h0.w, h1.x, h1.y, h1.z, h1.w};
            float ww[8] = {w0.x, w0.y, w0.z, w0.w, w1.x, w1.y, w1.z, w1.w};
            #pragma unroll
            for (int i = 0; i < 8; ++i)
                #pragma unroll
                for (int j = 0; j < 8; ++j)
                    acc[i][j] = fmaf(hh[i], ww[j], acc[i][j]);
        }
        __syncthreads();
    }

    // ---- epilogue ----
    #pragma unroll
    for (int i = 0; i < 8; ++i) {
        int r = rbase + rg * 8 + i;
        if (r < NROWS) {
            float4* op = (float4*)(out + (size_t)r * COUT + cg * 8);
            op[0] = make_float4(acc[i][0], acc[i][1], acc[i][2], acc[i][3]);
            op[1] = make_float4(acc[i][4], acc[i][5], acc[i][6], acc[i][7]);
        }
    }
}

extern "C" void kernel_launch(void* const* d_in, const int* in_sizes, int n_in,
                              void* d_out, int out_size, void* d_ws, size_t ws_size,
                              hipStream_t stream) {
    const float* feat = (const float*)d_in[0];
    const float* ef   = (const float*)d_in[1];
    const float* W    = (const float*)d_in[2];
    const float* b    = (const float*)d_in[3];
    const int*   src  = (const int*)d_in[4];
    const int*   dst  = (const int*)d_in[5];
    float* out = (float*)d_out;

    // Workspace: [FEATC NN*256][X1 2N*256][X2 2N*256][X3 2N*256][ints...]
    float* FEATC = (float*)d_ws;
    float* X1 = FEATC + SEG;
    float* X2 = X1 + (size_t)TWO_N * ROWF;
    float* X3 = X2 + (size_t)TWO_N * ROWF;
    int* row_ptr = (int*)(X3 + (size_t)TWO_N * ROWF);
    int* counts  = row_ptr + TWO_N + 64;
    int* ssrc    = counts  + TWO_N + 64;
    float* sef   = (float*)(ssrc + NEDGE);
    int* bsums   = (int*)(sef + NEDGE);

    copy_feat_kernel<<<(NN * ROWF / 4) / 256, 256, 0, stream>>>(feat, FEATC);

    hipMemsetAsync(counts, 0, TWO_N * sizeof(int), stream);
    hist_kernel<<<(NEDGE + 255) / 256, 256, 0, stream>>>(dst, counts);
    scan1_kernel<<<NBLK, SCAN_BS, 0, stream>>>(counts, row_ptr, bsums);
    scan2_kernel<<<1, 64, 0, stream>>>(bsums, row_ptr);
    scan3_kernel<<<NBLK, SCAN_BS, 0, stream>>>(row_ptr, bsums);
    hipMemsetAsync(counts, 0, TWO_N * sizeof(int), stream);
    scatter_kernel<<<(NEDGE + 255) / 256, 256, 0, stream>>>(src, dst, ef, row_ptr,
                                                            counts, ssrc, sef);

    int spmm_grid = (TWO_N + 3) / 4;
    spmm_kernel<<<spmm_grid, 256, 0, stream>>>(row_ptr, ssrc, sef,
                                               feat, 1, nullptr, 0, 1.0f, X1);
    spmm_kernel<<<spmm_grid, 256, 0, stream>>>(row_ptr, ssrc, sef,
                                               X1, 0, feat, 1, 2.0f, X2);
    spmm_kernel<<<spmm_grid, 256, 0, stream>>>(row_ptr, ssrc, sef,
                                               X2, 0, X1, 0, 2.0f, X3);

    // Output projection: tiled GEMM, 782 tiles of 256 rows
    out_gemm_kernel<<<(NROWS + BM - 1) / BM, 256, 0, stream>>>(FEATC, W, b, out);
}

// Round 10
// 359.840 us; speedup vs baseline: 2.6985x; 1.5740x over previous
//
#include <hip/hip_runtime.h>

#define NN      25000
#define TWO_N   50000
#define TT      8
#define CIN     32
#define ROWF    256      // TT*CIN elems per node row
#define COUT    64
#define FTOT    224
#define NEDGE   800000
#define NROWS   (NN * TT)            // 200000 output rows
#define SEGB    ((size_t)NN * ROWF)  // ushort elems per h-segment
#define SCAN_BS 1024
#define NBLK    ((TWO_N + SCAN_BS - 1) / SCAN_BS)   // 49

// out_gemm tiling
#define BM       256
#define BK       32
#define HS_PITCH 256   // k-major [32][256]; compute reads 8 uniq addrs/wave, 2-way max
#define WS_PITCH 64

__device__ __forceinline__ float bf2f(unsigned short u) {
    return __uint_as_float(((unsigned int)u) << 16);
}
__device__ __forceinline__ unsigned short f2bf(float f) {
    unsigned int x = __float_as_uint(f);
    return (unsigned short)((x + 0x7fffu + ((x >> 16) & 1u)) >> 16);   // RNE
}

// ---- CSR build ----
__global__ void hist_kernel(const int* __restrict__ dst, int* __restrict__ counts) {
    int i = blockIdx.x * blockDim.x + threadIdx.x;
    if (i < NEDGE) atomicAdd(&counts[dst[i]], 1);
}

__global__ void scan1_kernel(const int* __restrict__ counts, int* __restrict__ row_ptr,
                             int* __restrict__ bsums) {
    __shared__ int lds[SCAN_BS];
    int i = blockIdx.x * SCAN_BS + (int)threadIdx.x;
    int v = (i < TWO_N) ? counts[i] : 0;
    lds[threadIdx.x] = v;
    __syncthreads();
    for (int off = 1; off < SCAN_BS; off <<= 1) {
        int t = ((int)threadIdx.x >= off) ? lds[threadIdx.x - off] : 0;
        __syncthreads();
        lds[threadIdx.x] += t;
        __syncthreads();
    }
    if (i < TWO_N) row_ptr[i] = lds[threadIdx.x] - v;
    if (threadIdx.x == SCAN_BS - 1) bsums[blockIdx.x] = lds[SCAN_BS - 1];
}

__global__ void scan2_kernel(int* __restrict__ bsums, int* __restrict__ row_ptr) {
    int lane = threadIdx.x;
    int orig = (lane < NBLK) ? bsums[lane] : 0;
    int v = orig;
    for (int off = 1; off < 64; off <<= 1) {
        int t = __shfl_up(v, off);
        if (lane >= off) v += t;
    }
    if (lane < NBLK) bsums[lane] = v - orig;
    if (lane == NBLK - 1) row_ptr[TWO_N] = v;
}

__global__ void scan3_kernel(int* __restrict__ row_ptr, const int* __restrict__ bsums) {
    int i = blockIdx.x * SCAN_BS + (int)threadIdx.x;
    if (i < TWO_N) row_ptr[i] += bsums[blockIdx.x];
}

__global__ void scatter_kernel(const int* __restrict__ src, const int* __restrict__ dst,
                               const float* __restrict__ ef, const int* __restrict__ row_ptr,
                               int* __restrict__ fill, int* __restrict__ ssrc,
                               float* __restrict__ sef) {
    int i = blockIdx.x * blockDim.x + threadIdx.x;
    if (i < NEDGE) {
        int d = dst[i];
        int p = row_ptr[d] + atomicAdd(&fill[d], 1);
        ssrc[p] = src[i];
        sef[p]  = ef[i];
    }
}

// feat (f32) -> FEATB (bf16) in workspace
__global__ void feat2bf_kernel(const float* __restrict__ feat, ushort* __restrict__ dstp) {
    int i = blockIdx.x * blockDim.x + threadIdx.x;
    float4 v = ((const float4*)feat)[i];
    ushort4 o;
    o.x = f2bf(v.x); o.y = f2bf(v.y); o.z = f2bf(v.z); o.w = f2bf(v.w);
    ((ushort4*)dstp)[i] = o;
}

// ---- SpMM (bf16 storage, f32 accumulate): one wave per dst node.
// Gather row = 512B (lane: ushort4 = 8B, features 4L..4L+3). Halves the
// per-XCD operand refetch that bounds the f32 version (404 MB -> ~205 MB).
__global__ __launch_bounds__(256) void spmm_bf_kernel(
        const int* __restrict__ row_ptr, const int* __restrict__ ssrc,
        const float* __restrict__ sef,
        const ushort* __restrict__ hin, int wrap_in,
        const ushort* __restrict__ sub, int wrap_sub,
        float scale, ushort* __restrict__ out) {
    int wid  = (int)((blockIdx.x * blockDim.x + threadIdx.x) >> 6);
    int lane = threadIdx.x & 63;
    if (wid >= TWO_N) return;
    int beg = row_ptr[wid], end = row_ptr[wid + 1];
    float4 a0 = make_float4(0.f, 0.f, 0.f, 0.f);
    float4 a1 = a0, a2 = a0, a3 = a0;
    int e = beg;
    for (; e + 4 <= end; e += 4) {
        int s0 = ssrc[e], s1 = ssrc[e + 1], s2 = ssrc[e + 2], s3 = ssrc[e + 3];
        float w0 = sef[e], w1 = sef[e + 1], w2 = sef[e + 2], w3 = sef[e + 3];
        if (wrap_in) {
            if (s0 >= NN) s0 -= NN;
            if (s1 >= NN) s1 -= NN;
            if (s2 >= NN) s2 -= NN;
            if (s3 >= NN) s3 -= NN;
        }
        ushort4 v0 = ((const ushort4*)(hin + (size_t)s0 * ROWF))[lane];
        ushort4 v1 = ((const ushort4*)(hin + (size_t)s1 * ROWF))[lane];
        ushort4 v2 = ((const ushort4*)(hin + (size_t)s2 * ROWF))[lane];
        ushort4 v3 = ((const ushort4*)(hin + (size_t)s3 * ROWF))[lane];
        a0.x = fmaf(w0, bf2f(v0.x), a0.x); a0.y = fmaf(w0, bf2f(v0.y), a0.y);
        a0.z = fmaf(w0, bf2f(v0.z), a0.z); a0.w = fmaf(w0, bf2f(v0.w), a0.w);
        a1.x = fmaf(w1, bf2f(v1.x), a1.x); a1.y = fmaf(w1, bf2f(v1.y), a1.y);
        a1.z = fmaf(w1, bf2f(v1.z), a1.z); a1.w = fmaf(w1, bf2f(v1.w), a1.w);
        a2.x = fmaf(w2, bf2f(v2.x), a2.x); a2.y = fmaf(w2, bf2f(v2.y), a2.y);
        a2.z = fmaf(w2, bf2f(v2.z), a2.z); a2.w = fmaf(w2, bf2f(v2.w), a2.w);
        a3.x = fmaf(w3, bf2f(v3.x), a3.x); a3.y = fmaf(w3, bf2f(v3.y), a3.y);
        a3.z = fmaf(w3, bf2f(v3.z), a3.z); a3.w = fmaf(w3, bf2f(v3.w), a3.w);
    }
    for (; e < end; ++e) {
        int s = ssrc[e];
        float w = sef[e];
        if (wrap_in && s >= NN) s -= NN;
        ushort4 v = ((const ushort4*)(hin + (size_t)s * ROWF))[lane];
        a0.x = fmaf(w, bf2f(v.x), a0.x); a0.y = fmaf(w, bf2f(v.y), a0.y);
        a0.z = fmaf(w, bf2f(v.z), a0.z); a0.w = fmaf(w, bf2f(v.w), a0.w);
    }
    float4 acc;
    acc.x = (a0.x + a1.x) + (a2.x + a3.x);
    acc.y = (a0.y + a1.y) + (a2.y + a3.y);
    acc.z = (a0.z + a1.z) + (a2.z + a3.z);
    acc.w = (a0.w + a1.w) + (a2.w + a3.w);
    float4 r;
    if (sub != nullptr) {
        int sn = wid;
        if (wrap_sub && sn >= NN) sn -= NN;
        ushort4 sv = ((const ushort4*)(sub + (size_t)sn * ROWF))[lane];
        r.x = scale * acc.x - bf2f(sv.x);
        r.y = scale * acc.y - bf2f(sv.y);
        r.z = scale * acc.z - bf2f(sv.z);
        r.w = scale * acc.w - bf2f(sv.w);
    } else {
        r = acc;
    }
    ushort4 o;
    o.x = f2bf(r.x); o.y = f2bf(r.y); o.z = f2bf(r.z); o.w = f2bf(r.w);
    ((ushort4*)(out + (size_t)wid * ROWF))[lane] = o;
}

// ---- Output matmul: register-tiled GEMM, H in bf16 (converted to f32 in LDS).
// Layout: [FEATB NN][X1B 2N][X2B 2N][X3B 2N] rows of 32 bf16 -> segment a of
// (node,t)-row r lives at H + a*SEGB + r*32 (a = 0..6). Compute identical to r9.
__global__ __launch_bounds__(256, 2) void out_gemm_kernel(
        const ushort* __restrict__ H, const float* __restrict__ W,
        const float* __restrict__ b, float* __restrict__ out) {
    __shared__ float Hs[BK * HS_PITCH];   // 32768 B
    __shared__ float Ws[BK * WS_PITCH];   //  8192 B
    int tid = threadIdx.x;
    int rbase = blockIdx.x * BM;
    int rg = tid >> 3;          // row group 0..31
    int cg = tid & 7;           // col group 0..7

    float acc[8][8];
    {
        float4 b0 = ((const float4*)b)[cg * 2];
        float4 b1 = ((const float4*)b)[cg * 2 + 1];
        #pragma unroll
        for (int i = 0; i < 8; ++i) {
            acc[i][0] = b0.x; acc[i][1] = b0.y; acc[i][2] = b0.z; acc[i][3] = b0.w;
            acc[i][4] = b1.x; acc[i][5] = b1.y; acc[i][6] = b1.z; acc[i][7] = b1.w;
        }
    }

    int hbase4 = rg * 2;
    int wbase4 = cg * 2;

    #pragma unroll 1
    for (int a = 0; a < 7; ++a) {
        // ---- stage H tile: 256 rows x 32 bf16 = 16KB contiguous, coalesced ----
        const uint4* Hseg = (const uint4*)(H + (size_t)a * SEGB + (size_t)rbase * CIN);
        #pragma unroll
        for (int j = 0; j < 4; ++j) {
            int f = j * 256 + tid;            // uint4 index 0..1023; row r = f>>2
            int r = f >> 2, q8 = f & 3;       // q8: 8-feature group
            uint4 v = Hseg[f];
            int kbase = 8 * q8;
            Hs[(kbase + 0) * HS_PITCH + r] = __uint_as_float(v.x << 16);
            Hs[(kbase + 1) * HS_PITCH + r] = __uint_as_float(v.x & 0xffff0000u);
            Hs[(kbase + 2) * HS_PITCH + r] = __uint_as_float(v.y << 16);
            Hs[(kbase + 3) * HS_PITCH + r] = __uint_as_float(v.y & 0xffff0000u);
            Hs[(kbase + 4) * HS_PITCH + r] = __uint_as_float(v.z << 16);
            Hs[(kbase + 5) * HS_PITCH + r] = __uint_as_float(v.z & 0xffff0000u);
            Hs[(kbase + 6) * HS_PITCH + r] = __uint_as_float(v.w << 16);
            Hs[(kbase + 7) * HS_PITCH + r] = __uint_as_float(v.w & 0xffff0000u);
        }
        // ---- stage W tile: [32][64] f32, k-major in global ----
        const float4* W4 = (const float4*)(W + (size_t)a * CIN * COUT);
        #pragma unroll
        for (int j = 0; j < 2; ++j) {
            int f = j * 256 + tid;
            int k = f >> 4, cq = f & 15;
            ((float4*)&Ws[k * WS_PITCH])[cq] = W4[f];
        }
        __syncthreads();

        #pragma unroll 4
        for (int k = 0; k < BK; ++k) {
            const float4* hk = (const float4*)&Hs[k * HS_PITCH];
            const float4* wk = (const float4*)&Ws[k * WS_PITCH];
            float4 h0 = hk[hbase4], h1 = hk[hbase4 + 1];
            float4 w0 = wk[wbase4], w1 = wk[wbase4 + 1];
            float hh[8] = {h0.x, h0.y, h0.z, h0.w, h1.x, h1.y, h1.z, h1.w};
            float ww[8] = {w0.x, w0.y, w0.z, w0.w, w1.x, w1.y, w1.z, w1.w};
            #pragma unroll
            for (int i = 0; i < 8; ++i)
                #pragma unroll
                for (int j = 0; j < 8; ++j)
                    acc[i][j] = fmaf(hh[i], ww[j], acc[i][j]);
        }
        __syncthreads();
    }

    #pragma unroll
    for (int i = 0; i < 8; ++i) {
        int r = rbase + rg * 8 + i;
        if (r < NROWS) {
            float4* op = (float4*)(out + (size_t)r * COUT + cg * 8);
            op[0] = make_float4(acc[i][0], acc[i][1], acc[i][2], acc[i][3]);
            op[1] = make_float4(acc[i][4], acc[i][5], acc[i][6], acc[i][7]);
        }
    }
}

extern "C" void kernel_launch(void* const* d_in, const int* in_sizes, int n_in,
                              void* d_out, int out_size, void* d_ws, size_t ws_size,
                              hipStream_t stream) {
    const float* feat = (const float*)d_in[0];
    const float* ef   = (const float*)d_in[1];
    const float* W    = (const float*)d_in[2];
    const float* b    = (const float*)d_in[3];
    const int*   src  = (const int*)d_in[4];
    const int*   dst  = (const int*)d_in[5];
    float* out = (float*)d_out;

    // Workspace (bf16): [FEATB NN*256][X1B 2N*256][X2B 2N*256][X3B 2N*256] = 89.6 MB, then ints
    ushort* FEATB = (ushort*)d_ws;
    ushort* X1B = FEATB + SEGB;
    ushort* X2B = X1B + (size_t)TWO_N * ROWF;
    ushort* X3B = X2B + (size_t)TWO_N * ROWF;
    int* row_ptr = (int*)(X3B + (size_t)TWO_N * ROWF);
    int* counts  = row_ptr + TWO_N + 64;
    int* ssrc    = counts  + TWO_N + 64;
    float* sef   = (float*)(ssrc + NEDGE);
    int* bsums   = (int*)(sef + NEDGE);

    feat2bf_kernel<<<(NN * ROWF / 4) / 256, 256, 0, stream>>>(feat, FEATB);

    hipMemsetAsync(counts, 0, TWO_N * sizeof(int), stream);
    hist_kernel<<<(NEDGE + 255) / 256, 256, 0, stream>>>(dst, counts);
    scan1_kernel<<<NBLK, SCAN_BS, 0, stream>>>(counts, row_ptr, bsums);
    scan2_kernel<<<1, 64, 0, stream>>>(bsums, row_ptr);
    scan3_kernel<<<NBLK, SCAN_BS, 0, stream>>>(row_ptr, bsums);
    hipMemsetAsync(counts, 0, TWO_N * sizeof(int), stream);
    scatter_kernel<<<(NEDGE + 255) / 256, 256, 0, stream>>>(src, dst, ef, row_ptr,
                                                            counts, ssrc, sef);

    int spmm_grid = (TWO_N + 3) / 4;
    spmm_bf_kernel<<<spmm_grid, 256, 0, stream>>>(row_ptr, ssrc, sef,
                                                  FEATB, 1, nullptr, 0, 1.0f, X1B);
    spmm_bf_kernel<<<spmm_grid, 256, 0, stream>>>(row_ptr, ssrc, sef,
                                                  X1B, 0, FEATB, 1, 2.0f, X2B);
    spmm_bf_kernel<<<spmm_grid, 256, 0, stream>>>(row_ptr, ssrc, sef,
                                                  X2B, 0, X1B, 0, 2.0f, X3B);

    // Output projection: tiled GEMM, 782 tiles of 256 rows
    out_gemm_kernel<<<(NROWS + BM - 1) / BM, 256, 0, stream>>>(FEATB, W, b, out);
}

// Round 11
// 315.120 us; speedup vs baseline: 3.0814x; 1.1419x over previous
//
#include <hip/hip_runtime.h>

#define NN      25000
#define TWO_N   50000
#define TT      8
#define CIN     32
#define ROWF    256      // TT*CIN elems per node row
#define COUT    64
#define FTOT    224
#define NEDGE   800000
#define NROWS   (NN * TT)            // 200000 output rows (= 12500 x 16 exactly)
#define SEGB    ((size_t)NN * ROWF)  // ushort elems per h-segment
#define SCAN_BS 1024
#define NBLK    ((TWO_N + SCAN_BS - 1) / SCAN_BS)   // 49

typedef __attribute__((ext_vector_type(8))) short short8v;   // bf16x8 MFMA frag (4 VGPR)
typedef __attribute__((ext_vector_type(4))) float f32x4;     // MFMA accumulator

__device__ __forceinline__ float bf2f(unsigned short u) {
    return __uint_as_float(((unsigned int)u) << 16);
}
__device__ __forceinline__ unsigned short f2bf(float f) {
    unsigned int x = __float_as_uint(f);
    return (unsigned short)((x + 0x7fffu + ((x >> 16) & 1u)) >> 16);   // RNE
}

// ---- CSR build ----
__global__ void hist_kernel(const int* __restrict__ dst, int* __restrict__ counts) {
    int i = blockIdx.x * blockDim.x + threadIdx.x;
    if (i < NEDGE) atomicAdd(&counts[dst[i]], 1);
}

__global__ void scan1_kernel(const int* __restrict__ counts, int* __restrict__ row_ptr,
                             int* __restrict__ bsums) {
    __shared__ int lds[SCAN_BS];
    int i = blockIdx.x * SCAN_BS + (int)threadIdx.x;
    int v = (i < TWO_N) ? counts[i] : 0;
    lds[threadIdx.x] = v;
    __syncthreads();
    for (int off = 1; off < SCAN_BS; off <<= 1) {
        int t = ((int)threadIdx.x >= off) ? lds[threadIdx.x - off] : 0;
        __syncthreads();
        lds[threadIdx.x] += t;
        __syncthreads();
    }
    if (i < TWO_N) row_ptr[i] = lds[threadIdx.x] - v;
    if (threadIdx.x == SCAN_BS - 1) bsums[blockIdx.x] = lds[SCAN_BS - 1];
}

__global__ void scan2_kernel(int* __restrict__ bsums, int* __restrict__ row_ptr) {
    int lane = threadIdx.x;
    int orig = (lane < NBLK) ? bsums[lane] : 0;
    int v = orig;
    for (int off = 1; off < 64; off <<= 1) {
        int t = __shfl_up(v, off);
        if (lane >= off) v += t;
    }
    if (lane < NBLK) bsums[lane] = v - orig;
    if (lane == NBLK - 1) row_ptr[TWO_N] = v;
}

__global__ void scan3_kernel(int* __restrict__ row_ptr, const int* __restrict__ bsums) {
    int i = blockIdx.x * SCAN_BS + (int)threadIdx.x;
    if (i < TWO_N) row_ptr[i] += bsums[blockIdx.x];
}

__global__ void scatter_kernel(const int* __restrict__ src, const int* __restrict__ dst,
                               const float* __restrict__ ef, const int* __restrict__ row_ptr,
                               int* __restrict__ fill, int* __restrict__ ssrc,
                               float* __restrict__ sef) {
    int i = blockIdx.x * blockDim.x + threadIdx.x;
    if (i < NEDGE) {
        int d = dst[i];
        int p = row_ptr[d] + atomicAdd(&fill[d], 1);
        ssrc[p] = src[i];
        sef[p]  = ef[i];
    }
}

// feat (f32) -> FEATB (bf16)
__global__ void feat2bf_kernel(const float* __restrict__ feat, ushort* __restrict__ dstp) {
    int i = blockIdx.x * blockDim.x + threadIdx.x;
    float4 v = ((const float4*)feat)[i];
    ushort4 o;
    o.x = f2bf(v.x); o.y = f2bf(v.y); o.z = f2bf(v.z); o.w = f2bf(v.w);
    ((ushort4*)dstp)[i] = o;
}

// W (f32 [224][64]) -> bf16 in MFMA B-fragment order:
// Wp[((a*4+ct)*64 + lane)*8 + j] = W[a*32 + (lane>>4)*8 + j][ct*16 + (lane&15)]
__global__ void packW_kernel(const float* __restrict__ W, ushort* __restrict__ Wp) {
    int i = blockIdx.x * blockDim.x + threadIdx.x;
    if (i >= 7 * 4 * 64 * 8) return;
    int j  = i & 7;
    int l  = (i >> 3) & 63;
    int ct = (i >> 9) & 3;
    int a  = i >> 11;
    int k   = (l >> 4) * 8 + j;
    int col = ct * 16 + (l & 15);
    Wp[i] = f2bf(W[(a * 32 + k) * COUT + col]);
}

// ---- SpMM (bf16 storage, f32 accumulate): one wave per dst node ----
__global__ __launch_bounds__(256) void spmm_bf_kernel(
        const int* __restrict__ row_ptr, const int* __restrict__ ssrc,
        const float* __restrict__ sef,
        const ushort* __restrict__ hin, int wrap_in,
        const ushort* __restrict__ sub, int wrap_sub,
        float scale, ushort* __restrict__ out) {
    int wid  = (int)((blockIdx.x * blockDim.x + threadIdx.x) >> 6);
    int lane = threadIdx.x & 63;
    if (wid >= TWO_N) return;
    int beg = row_ptr[wid], end = row_ptr[wid + 1];
    float4 a0 = make_float4(0.f, 0.f, 0.f, 0.f);
    float4 a1 = a0, a2 = a0, a3 = a0;
    int e = beg;
    for (; e + 4 <= end; e += 4) {
        int s0 = ssrc[e], s1 = ssrc[e + 1], s2 = ssrc[e + 2], s3 = ssrc[e + 3];
        float w0 = sef[e], w1 = sef[e + 1], w2 = sef[e + 2], w3 = sef[e + 3];
        if (wrap_in) {
            if (s0 >= NN) s0 -= NN;
            if (s1 >= NN) s1 -= NN;
            if (s2 >= NN) s2 -= NN;
            if (s3 >= NN) s3 -= NN;
        }
        ushort4 v0 = ((const ushort4*)(hin + (size_t)s0 * ROWF))[lane];
        ushort4 v1 = ((const ushort4*)(hin + (size_t)s1 * ROWF))[lane];
        ushort4 v2 = ((const ushort4*)(hin + (size_t)s2 * ROWF))[lane];
        ushort4 v3 = ((const ushort4*)(hin + (size_t)s3 * ROWF))[lane];
        a0.x = fmaf(w0, bf2f(v0.x), a0.x); a0.y = fmaf(w0, bf2f(v0.y), a0.y);
        a0.z = fmaf(w0, bf2f(v0.z), a0.z); a0.w = fmaf(w0, bf2f(v0.w), a0.w);
        a1.x = fmaf(w1, bf2f(v1.x), a1.x); a1.y = fmaf(w1, bf2f(v1.y), a1.y);
        a1.z = fmaf(w1, bf2f(v1.z), a1.z); a1.w = fmaf(w1, bf2f(v1.w), a1.w);
        a2.x = fmaf(w2, bf2f(v2.x), a2.x); a2.y = fmaf(w2, bf2f(v2.y), a2.y);
        a2.z = fmaf(w2, bf2f(v2.z), a2.z); a2.w = fmaf(w2, bf2f(v2.w), a2.w);
        a3.x = fmaf(w3, bf2f(v3.x), a3.x); a3.y = fmaf(w3, bf2f(v3.y), a3.y);
        a3.z = fmaf(w3, bf2f(v3.z), a3.z); a3.w = fmaf(w3, bf2f(v3.w), a3.w);
    }
    for (; e < end; ++e) {
        int s = ssrc[e];
        float w = sef[e];
        if (wrap_in && s >= NN) s -= NN;
        ushort4 v = ((const ushort4*)(hin + (size_t)s * ROWF))[lane];
        a0.x = fmaf(w, bf2f(v.x), a0.x); a0.y = fmaf(w, bf2f(v.y), a0.y);
        a0.z = fmaf(w, bf2f(v.z), a0.z); a0.w = fmaf(w, bf2f(v.w), a0.w);
    }
    float4 acc;
    acc.x = (a0.x + a1.x) + (a2.x + a3.x);
    acc.y = (a0.y + a1.y) + (a2.y + a3.y);
    acc.z = (a0.z + a1.z) + (a2.z + a3.z);
    acc.w = (a0.w + a1.w) + (a2.w + a3.w);
    float4 r;
    if (sub != nullptr) {
        int sn = wid;
        if (wrap_sub && sn >= NN) sn -= NN;
        ushort4 sv = ((const ushort4*)(sub + (size_t)sn * ROWF))[lane];
        r.x = scale * acc.x - bf2f(sv.x);
        r.y = scale * acc.y - bf2f(sv.y);
        r.z = scale * acc.z - bf2f(sv.z);
        r.w = scale * acc.w - bf2f(sv.w);
    } else {
        r = acc;
    }
    ushort4 o;
    o.x = f2bf(r.x); o.y = f2bf(r.y); o.z = f2bf(r.z); o.w = f2bf(r.w);
    ((ushort4*)(out + (size_t)wid * ROWF))[lane] = o;
}

// ---- Output matmul on MATRIX CORES: one wave per 16-row tile, no LDS.
// A-frag: lane l reads H[rbase+(l&15)] seg a, k-chunk (l>>4)*8 -> 16B contiguous
// (4-lane clusters cover full 64B rows: coalesced). B-frag: Wp pre-packed in
// fragment order, wp[lane] (L2-broadcast-hot). Any within-k permutation error in
// the assumed A/B map cancels (same map both operands); C/D map is the
// m89-VERIFIED col=lane&15, row=(lane>>4)*4+reg.
__global__ __launch_bounds__(256) void out_mfma_kernel(
        const ushort* __restrict__ H, const ushort* __restrict__ Wp,
        const float* __restrict__ b, float* __restrict__ out) {
    int wave = (int)((blockIdx.x * blockDim.x + threadIdx.x) >> 6);
    int lane = threadIdx.x & 63;
    if (wave >= NROWS / 16) return;
    int rbase = wave * 16;
    int row = lane & 15;
    int kb  = lane >> 4;

    f32x4 acc[4];
    #pragma unroll
    for (int ct = 0; ct < 4; ++ct) {
        float bv = b[ct * 16 + row];
        acc[ct][0] = bv; acc[ct][1] = bv; acc[ct][2] = bv; acc[ct][3] = bv;
    }

    const ushort* ha = H + (size_t)(rbase + row) * CIN + kb * 8;
    #pragma unroll
    for (int a = 0; a < 7; ++a) {
        short8v af = *(const short8v*)(ha + (size_t)a * SEGB);
        const short8v* wp = (const short8v*)(Wp + (size_t)a * 2048);
        acc[0] = __builtin_amdgcn_mfma_f32_16x16x32_bf16(af, wp[0 * 64 + lane], acc[0], 0, 0, 0);
        acc[1] = __builtin_amdgcn_mfma_f32_16x16x32_bf16(af, wp[1 * 64 + lane], acc[1], 0, 0, 0);
        acc[2] = __builtin_amdgcn_mfma_f32_16x16x32_bf16(af, wp[2 * 64 + lane], acc[2], 0, 0, 0);
        acc[3] = __builtin_amdgcn_mfma_f32_16x16x32_bf16(af, wp[3 * 64 + lane], acc[3], 0, 0, 0);
    }

    // C/D: col = lane&15, row = (lane>>4)*4 + reg  [verified m89]
    int orow = rbase + kb * 4;
    #pragma unroll
    for (int ct = 0; ct < 4; ++ct) {
        int col = ct * 16 + row;
        #pragma unroll
        for (int r = 0; r < 4; ++r)
            out[(size_t)(orow + r) * COUT + col] = acc[ct][r];
    }
}

extern "C" void kernel_launch(void* const* d_in, const int* in_sizes, int n_in,
                              void* d_out, int out_size, void* d_ws, size_t ws_size,
                              hipStream_t stream) {
    const float* feat = (const float*)d_in[0];
    const float* ef   = (const float*)d_in[1];
    const float* W    = (const float*)d_in[2];
    const float* b    = (const float*)d_in[3];
    const int*   src  = (const int*)d_in[4];
    const int*   dst  = (const int*)d_in[5];
    float* out = (float*)d_out;

    // Workspace: [FEATB][X1B][X2B][X3B] bf16 (89.6 MB), [Wp 28.7KB], ints
    ushort* FEATB = (ushort*)d_ws;
    ushort* X1B = FEATB + SEGB;
    ushort* X2B = X1B + (size_t)TWO_N * ROWF;
    ushort* X3B = X2B + (size_t)TWO_N * ROWF;
    ushort* Wp  = X3B + (size_t)TWO_N * ROWF;
    int* row_ptr = (int*)(Wp + 7 * 4 * 64 * 8);
    int* counts  = row_ptr + TWO_N + 64;
    int* ssrc    = counts  + TWO_N + 64;
    float* sef   = (float*)(ssrc + NEDGE);
    int* bsums   = (int*)(sef + NEDGE);

    feat2bf_kernel<<<(NN * ROWF / 4) / 256, 256, 0, stream>>>(feat, FEATB);
    packW_kernel<<<56, 256, 0, stream>>>(W, Wp);

    hipMemsetAsync(counts, 0, TWO_N * sizeof(int), stream);
    hist_kernel<<<(NEDGE + 255) / 256, 256, 0, stream>>>(dst, counts);
    scan1_kernel<<<NBLK, SCAN_BS, 0, stream>>>(counts, row_ptr, bsums);
    scan2_kernel<<<1, 64, 0, stream>>>(bsums, row_ptr);
    scan3_kernel<<<NBLK, SCAN_BS, 0, stream>>>(row_ptr, bsums);
    hipMemsetAsync(counts, 0, TWO_N * sizeof(int), stream);
    scatter_kernel<<<(NEDGE + 255) / 256, 256, 0, stream>>>(src, dst, ef, row_ptr,
                                                            counts, ssrc, sef);

    int spmm_grid = (TWO_N + 3) / 4;
    spmm_bf_kernel<<<spmm_grid, 256, 0, stream>>>(row_ptr, ssrc, sef,
                                                  FEATB, 1, nullptr, 0, 1.0f, X1B);
    spmm_bf_kernel<<<spmm_grid, 256, 0, stream>>>(row_ptr, ssrc, sef,
                                                  X1B, 0, FEATB, 1, 2.0f, X2B);
    spmm_bf_kernel<<<spmm_grid, 256, 0, stream>>>(row_ptr, ssrc, sef,
                                                  X2B, 0, X1B, 0, 2.0f, X3B);

    // Output projection: MFMA, 12500 waves = 3125 blocks x 4 waves
    out_mfma_kernel<<<3125, 256, 0, stream>>>(FEATB, Wp, b, out);
}

// Round 12
// 260.277 us; speedup vs baseline: 3.7307x; 1.2107x over previous
//
#include <hip/hip_runtime.h>

#define NN      25000
#define TWO_N   50000
#define TT      8
#define CIN     32
#define ROWF    256      // TT*CIN elems per node row
#define COUT    64
#define FTOT    224
#define NEDGE   800000
#define NROWS   (NN * TT)            // 200000 output rows (= 12500 x 16 exactly)
#define SEGB    ((size_t)NN * ROWF)  // ushort elems per h-segment
#define BUCK    64                   // padded bucket slots per dst (P(deg>64)~1e-18)

typedef __attribute__((ext_vector_type(8))) short short8v;   // bf16x8 MFMA frag
typedef __attribute__((ext_vector_type(4))) float f32x4;     // MFMA accumulator

__device__ __forceinline__ float bf2f(unsigned short u) {
    return __uint_as_float(((unsigned int)u) << 16);
}
__device__ __forceinline__ unsigned short f2bf(float f) {
    unsigned int x = __float_as_uint(f);
    return (unsigned short)((x + 0x7fffu + ((x >> 16) & 1u)) >> 16);   // RNE
}

// ---- bucket scatter: one pass, no hist/scan. edges[d*64+c] = {src, ef} ----
__global__ void scatter_kernel(const int* __restrict__ src, const int* __restrict__ dst,
                               const float* __restrict__ ef,
                               int* __restrict__ counts, int2* __restrict__ edges) {
    int i = blockIdx.x * blockDim.x + threadIdx.x;
    if (i < NEDGE) {
        int d = dst[i];
        int c = atomicAdd(&counts[d], 1);
        if (c < BUCK)
            edges[(size_t)d * BUCK + c] = make_int2(src[i], __float_as_int(ef[i]));
    }
}

// feat (f32) -> FEATB (bf16)
__global__ void feat2bf_kernel(const float* __restrict__ feat, ushort* __restrict__ dstp) {
    int i = blockIdx.x * blockDim.x + threadIdx.x;
    float4 v = ((const float4*)feat)[i];
    ushort4 o;
    o.x = f2bf(v.x); o.y = f2bf(v.y); o.z = f2bf(v.z); o.w = f2bf(v.w);
    ((ushort4*)dstp)[i] = o;
}

// W (f32 [224][64]) -> bf16 in MFMA B-fragment order:
// Wp[((a*4+ct)*64 + lane)*8 + j] = W[a*32 + (lane>>4)*8 + j][ct*16 + (lane&15)]
__global__ void packW_kernel(const float* __restrict__ W, ushort* __restrict__ Wp) {
    int i = blockIdx.x * blockDim.x + threadIdx.x;
    if (i >= 7 * 4 * 64 * 8) return;
    int j  = i & 7;
    int l  = (i >> 3) & 63;
    int ct = (i >> 9) & 3;
    int a  = i >> 11;
    int k   = (l >> 4) * 8 + j;
    int col = ct * 16 + (l & 15);
    Wp[i] = f2bf(W[(a * 32 + k) * COUT + col]);
}

// ---- SpMM (bf16 storage, f32 accumulate): one wave per dst node, bucket CSR ----
__global__ __launch_bounds__(256) void spmm_bf_kernel(
        const int* __restrict__ counts, const int2* __restrict__ edges,
        const ushort* __restrict__ hin, int wrap_in,
        const ushort* __restrict__ sub, int wrap_sub,
        float scale, ushort* __restrict__ out) {
    int wid  = (int)((blockIdx.x * blockDim.x + threadIdx.x) >> 6);
    int lane = threadIdx.x & 63;
    if (wid >= TWO_N) return;
    int cnt = counts[wid];
    if (cnt > BUCK) cnt = BUCK;
    const int2* el = edges + (size_t)wid * BUCK;
    float4 a0 = make_float4(0.f, 0.f, 0.f, 0.f);
    float4 a1 = a0, a2 = a0, a3 = a0;
    int e = 0;
    for (; e + 4 <= cnt; e += 4) {
        int2 e0 = el[e], e1 = el[e + 1], e2 = el[e + 2], e3 = el[e + 3];
        int s0 = e0.x, s1 = e1.x, s2 = e2.x, s3 = e3.x;
        float w0 = __int_as_float(e0.y), w1 = __int_as_float(e1.y);
        float w2 = __int_as_float(e2.y), w3 = __int_as_float(e3.y);
        if (wrap_in) {
            if (s0 >= NN) s0 -= NN;
            if (s1 >= NN) s1 -= NN;
            if (s2 >= NN) s2 -= NN;
            if (s3 >= NN) s3 -= NN;
        }
        ushort4 v0 = ((const ushort4*)(hin + (size_t)s0 * ROWF))[lane];
        ushort4 v1 = ((const ushort4*)(hin + (size_t)s1 * ROWF))[lane];
        ushort4 v2 = ((const ushort4*)(hin + (size_t)s2 * ROWF))[lane];
        ushort4 v3 = ((const ushort4*)(hin + (size_t)s3 * ROWF))[lane];
        a0.x = fmaf(w0, bf2f(v0.x), a0.x); a0.y = fmaf(w0, bf2f(v0.y), a0.y);
        a0.z = fmaf(w0, bf2f(v0.z), a0.z); a0.w = fmaf(w0, bf2f(v0.w), a0.w);
        a1.x = fmaf(w1, bf2f(v1.x), a1.x); a1.y = fmaf(w1, bf2f(v1.y), a1.y);
        a1.z = fmaf(w1, bf2f(v1.z), a1.z); a1.w = fmaf(w1, bf2f(v1.w), a1.w);
        a2.x = fmaf(w2, bf2f(v2.x), a2.x); a2.y = fmaf(w2, bf2f(v2.y), a2.y);
        a2.z = fmaf(w2, bf2f(v2.z), a2.z); a2.w = fmaf(w2, bf2f(v2.w), a2.w);
        a3.x = fmaf(w3, bf2f(v3.x), a3.x); a3.y = fmaf(w3, bf2f(v3.y), a3.y);
        a3.z = fmaf(w3, bf2f(v3.z), a3.z); a3.w = fmaf(w3, bf2f(v3.w), a3.w);
    }
    for (; e < cnt; ++e) {
        int2 ed = el[e];
        int s = ed.x;
        float w = __int_as_float(ed.y);
        if (wrap_in && s >= NN) s -= NN;
        ushort4 v = ((const ushort4*)(hin + (size_t)s * ROWF))[lane];
        a0.x = fmaf(w, bf2f(v.x), a0.x); a0.y = fmaf(w, bf2f(v.y), a0.y);
        a0.z = fmaf(w, bf2f(v.z), a0.z); a0.w = fmaf(w, bf2f(v.w), a0.w);
    }
    float4 acc;
    acc.x = (a0.x + a1.x) + (a2.x + a3.x);
    acc.y = (a0.y + a1.y) + (a2.y + a3.y);
    acc.z = (a0.z + a1.z) + (a2.z + a3.z);
    acc.w = (a0.w + a1.w) + (a2.w + a3.w);
    float4 r;
    if (sub != nullptr) {
        int sn = wid;
        if (wrap_sub && sn >= NN) sn -= NN;
        ushort4 sv = ((const ushort4*)(sub + (size_t)sn * ROWF))[lane];
        r.x = scale * acc.x - bf2f(sv.x);
        r.y = scale * acc.y - bf2f(sv.y);
        r.z = scale * acc.z - bf2f(sv.z);
        r.w = scale * acc.w - bf2f(sv.w);
    } else {
        r = acc;
    }
    ushort4 o;
    o.x = f2bf(r.x); o.y = f2bf(r.y); o.z = f2bf(r.z); o.w = f2bf(r.w);
    ((ushort4*)(out + (size_t)wid * ROWF))[lane] = o;
}

// ---- Output matmul on MATRIX CORES: one wave per 16-row tile, no LDS. ----
__global__ __launch_bounds__(256) void out_mfma_kernel(
        const ushort* __restrict__ H, const ushort* __restrict__ Wp,
        const float* __restrict__ b, float* __restrict__ out) {
    int wave = (int)((blockIdx.x * blockDim.x + threadIdx.x) >> 6);
    int lane = threadIdx.x & 63;
    if (wave >= NROWS / 16) return;
    int rbase = wave * 16;
    int row = lane & 15;
    int kb  = lane >> 4;

    f32x4 acc[4];
    #pragma unroll
    for (int ct = 0; ct < 4; ++ct) {
        float bv = b[ct * 16 + row];
        acc[ct][0] = bv; acc[ct][1] = bv; acc[ct][2] = bv; acc[ct][3] = bv;
    }

    const ushort* ha = H + (size_t)(rbase + row) * CIN + kb * 8;
    #pragma unroll
    for (int a = 0; a < 7; ++a) {
        short8v af = *(const short8v*)(ha + (size_t)a * SEGB);
        const short8v* wp = (const short8v*)(Wp + (size_t)a * 2048);
        acc[0] = __builtin_amdgcn_mfma_f32_16x16x32_bf16(af, wp[0 * 64 + lane], acc[0], 0, 0, 0);
        acc[1] = __builtin_amdgcn_mfma_f32_16x16x32_bf16(af, wp[1 * 64 + lane], acc[1], 0, 0, 0);
        acc[2] = __builtin_amdgcn_mfma_f32_16x16x32_bf16(af, wp[2 * 64 + lane], acc[2], 0, 0, 0);
        acc[3] = __builtin_amdgcn_mfma_f32_16x16x32_bf16(af, wp[3 * 64 + lane], acc[3], 0, 0, 0);
    }

    // C/D: col = lane&15, row = (lane>>4)*4 + reg  [verified m89]
    int orow = rbase + kb * 4;
    #pragma unroll
    for (int ct = 0; ct < 4; ++ct) {
        int col = ct * 16 + row;
        #pragma unroll
        for (int r = 0; r < 4; ++r)
            out[(size_t)(orow + r) * COUT + col] = acc[ct][r];
    }
}

extern "C" void kernel_launch(void* const* d_in, const int* in_sizes, int n_in,
                              void* d_out, int out_size, void* d_ws, size_t ws_size,
                              hipStream_t stream) {
    const float* feat = (const float*)d_in[0];
    const float* ef   = (const float*)d_in[1];
    const float* W    = (const float*)d_in[2];
    const float* b    = (const float*)d_in[3];
    const int*   src  = (const int*)d_in[4];
    const int*   dst  = (const int*)d_in[5];
    float* out = (float*)d_out;

    // Workspace: [FEATB][X1B][X2B][X3B] bf16 (89.6 MB), [Wp], [counts], [edges 25.6 MB]
    ushort* FEATB = (ushort*)d_ws;
    ushort* X1B = FEATB + SEGB;
    ushort* X2B = X1B + (size_t)TWO_N * ROWF;
    ushort* X3B = X2B + (size_t)TWO_N * ROWF;
    ushort* Wp  = X3B + (size_t)TWO_N * ROWF;
    int*  counts = (int*)(Wp + 7 * 4 * 64 * 8);
    int2* edges  = (int2*)(counts + TWO_N + 64);

    feat2bf_kernel<<<(NN * ROWF / 4) / 256, 256, 0, stream>>>(feat, FEATB);
    packW_kernel<<<56, 256, 0, stream>>>(W, Wp);

    hipMemsetAsync(counts, 0, TWO_N * sizeof(int), stream);
    scatter_kernel<<<(NEDGE + 255) / 256, 256, 0, stream>>>(src, dst, ef, counts, edges);

    int spmm_grid = (TWO_N + 3) / 4;
    spmm_bf_kernel<<<spmm_grid, 256, 0, stream>>>(counts, edges,
                                                  FEATB, 1, nullptr, 0, 1.0f, X1B);
    spmm_bf_kernel<<<spmm_grid, 256, 0, stream>>>(counts, edges,
                                                  X1B, 0, FEATB, 1, 2.0f, X2B);
    spmm_bf_kernel<<<spmm_grid, 256, 0, stream>>>(counts, edges,
                                                  X2B, 0, X1B, 0, 2.0f, X3B);

    // Output projection: MFMA, 12500 waves = 3125 blocks x 4 waves
    out_mfma_kernel<<<3125, 256, 0, stream>>>(FEATB, Wp, b, out);
}

// Round 13
// 257.354 us; speedup vs baseline: 3.7731x; 1.0114x over previous
//
#include <hip/hip_runtime.h>

#define NN      25000
#define TWO_N   50000
#define TT      8
#define CIN     32
#define ROWF    256      // TT*CIN elems per node row
#define COUT    64
#define FTOT    224
#define NEDGE   800000
#define NROWS   (NN * TT)            // 200000 output rows (= 12500 x 16 exactly)
#define SEGB    ((size_t)NN * ROWF)  // ushort elems per h-segment
#define BUCK    64                   // padded bucket slots per dst (P(deg>64)~1e-18)

typedef __attribute__((ext_vector_type(8))) short short8v;   // bf16x8 MFMA frag
typedef __attribute__((ext_vector_type(4))) float f32x4;     // MFMA accumulator

__device__ __forceinline__ float bf2f(unsigned short u) {
    return __uint_as_float(((unsigned int)u) << 16);
}
__device__ __forceinline__ unsigned short f2bf(float f) {
    unsigned int x = __float_as_uint(f);
    return (unsigned short)((x + 0x7fffu + ((x >> 16) & 1u)) >> 16);   // RNE
}

// ---- bucket scatter: one pass. edge record = 4B: (bf16(ef)<<16) | src ----
__global__ void scatter_kernel(const int* __restrict__ src, const int* __restrict__ dst,
                               const float* __restrict__ ef,
                               int* __restrict__ counts, unsigned int* __restrict__ edges) {
    int i = blockIdx.x * blockDim.x + threadIdx.x;
    if (i < NEDGE) {
        int d = dst[i];
        int c = atomicAdd(&counts[d], 1);
        if (c < BUCK) {
            unsigned int rec = ((unsigned int)f2bf(ef[i]) << 16) | (unsigned int)src[i];
            edges[(size_t)d * BUCK + c] = rec;
        }
    }
}

// feat (f32) -> FEATB (bf16)
__global__ void feat2bf_kernel(const float* __restrict__ feat, ushort* __restrict__ dstp) {
    int i = blockIdx.x * blockDim.x + threadIdx.x;
    float4 v = ((const float4*)feat)[i];
    ushort4 o;
    o.x = f2bf(v.x); o.y = f2bf(v.y); o.z = f2bf(v.z); o.w = f2bf(v.w);
    ((ushort4*)dstp)[i] = o;
}

// W (f32 [224][64]) -> bf16 in MFMA B-fragment order:
// Wp[((a*4+ct)*64 + lane)*8 + j] = W[a*32 + (lane>>4)*8 + j][ct*16 + (lane&15)]
__global__ void packW_kernel(const float* __restrict__ W, ushort* __restrict__ Wp) {
    int i = blockIdx.x * blockDim.x + threadIdx.x;
    if (i >= 7 * 4 * 64 * 8) return;
    int j  = i & 7;
    int l  = (i >> 3) & 63;
    int ct = (i >> 9) & 3;
    int a  = i >> 11;
    int k   = (l >> 4) * 8 + j;
    int col = ct * 16 + (l & 15);
    Wp[i] = f2bf(W[(a * 32 + k) * COUT + col]);
}

// ---- SpMM (bf16 storage, f32 accumulate): one wave per dst node, bucket CSR.
// Edge records are wave-uniform scalar loads; 8 gathers in flight per iter.
__global__ __launch_bounds__(256) void spmm_bf_kernel(
        const int* __restrict__ counts, const unsigned int* __restrict__ edges,
        const ushort* __restrict__ hin, int wrap_in,
        const ushort* __restrict__ sub, int wrap_sub,
        float scale, ushort* __restrict__ out) {
    int wid  = (int)((blockIdx.x * blockDim.x + threadIdx.x) >> 6);
    int lane = threadIdx.x & 63;
    if (wid >= TWO_N) return;
    int cnt = counts[wid];
    if (cnt > BUCK) cnt = BUCK;
    const unsigned int* el = edges + (size_t)wid * BUCK;
    float4 a0 = make_float4(0.f, 0.f, 0.f, 0.f);
    float4 a1 = a0, a2 = a0, a3 = a0;
    int e = 0;
    for (; e + 8 <= cnt; e += 8) {
        unsigned int r0 = el[e], r1 = el[e+1], r2 = el[e+2], r3 = el[e+3];
        unsigned int r4 = el[e+4], r5 = el[e+5], r6 = el[e+6], r7 = el[e+7];
        int s0 = r0 & 0xffff, s1 = r1 & 0xffff, s2 = r2 & 0xffff, s3 = r3 & 0xffff;
        int s4 = r4 & 0xffff, s5 = r5 & 0xffff, s6 = r6 & 0xffff, s7 = r7 & 0xffff;
        if (wrap_in) {
            if (s0 >= NN) s0 -= NN;  if (s1 >= NN) s1 -= NN;
            if (s2 >= NN) s2 -= NN;  if (s3 >= NN) s3 -= NN;
            if (s4 >= NN) s4 -= NN;  if (s5 >= NN) s5 -= NN;
            if (s6 >= NN) s6 -= NN;  if (s7 >= NN) s7 -= NN;
        }
        ushort4 v0 = ((const ushort4*)(hin + (size_t)s0 * ROWF))[lane];
        ushort4 v1 = ((const ushort4*)(hin + (size_t)s1 * ROWF))[lane];
        ushort4 v2 = ((const ushort4*)(hin + (size_t)s2 * ROWF))[lane];
        ushort4 v3 = ((const ushort4*)(hin + (size_t)s3 * ROWF))[lane];
        ushort4 v4 = ((const ushort4*)(hin + (size_t)s4 * ROWF))[lane];
        ushort4 v5 = ((const ushort4*)(hin + (size_t)s5 * ROWF))[lane];
        ushort4 v6 = ((const ushort4*)(hin + (size_t)s6 * ROWF))[lane];
        ushort4 v7 = ((const ushort4*)(hin + (size_t)s7 * ROWF))[lane];
        float w0 = bf2f(r0 >> 16), w1 = bf2f(r1 >> 16);
        float w2 = bf2f(r2 >> 16), w3 = bf2f(r3 >> 16);
        float w4 = bf2f(r4 >> 16), w5 = bf2f(r5 >> 16);
        float w6 = bf2f(r6 >> 16), w7 = bf2f(r7 >> 16);
        a0.x = fmaf(w0, bf2f(v0.x), a0.x); a0.y = fmaf(w0, bf2f(v0.y), a0.y);
        a0.z = fmaf(w0, bf2f(v0.z), a0.z); a0.w = fmaf(w0, bf2f(v0.w), a0.w);
        a1.x = fmaf(w1, bf2f(v1.x), a1.x); a1.y = fmaf(w1, bf2f(v1.y), a1.y);
        a1.z = fmaf(w1, bf2f(v1.z), a1.z); a1.w = fmaf(w1, bf2f(v1.w), a1.w);
        a2.x = fmaf(w2, bf2f(v2.x), a2.x); a2.y = fmaf(w2, bf2f(v2.y), a2.y);
        a2.z = fmaf(w2, bf2f(v2.z), a2.z); a2.w = fmaf(w2, bf2f(v2.w), a2.w);
        a3.x = fmaf(w3, bf2f(v3.x), a3.x); a3.y = fmaf(w3, bf2f(v3.y), a3.y);
        a3.z = fmaf(w3, bf2f(v3.z), a3.z); a3.w = fmaf(w3, bf2f(v3.w), a3.w);
        a0.x = fmaf(w4, bf2f(v4.x), a0.x); a0.y = fmaf(w4, bf2f(v4.y), a0.y);
        a0.z = fmaf(w4, bf2f(v4.z), a0.z); a0.w = fmaf(w4, bf2f(v4.w), a0.w);
        a1.x = fmaf(w5, bf2f(v5.x), a1.x); a1.y = fmaf(w5, bf2f(v5.y), a1.y);
        a1.z = fmaf(w5, bf2f(v5.z), a1.z); a1.w = fmaf(w5, bf2f(v5.w), a1.w);
        a2.x = fmaf(w6, bf2f(v6.x), a2.x); a2.y = fmaf(w6, bf2f(v6.y), a2.y);
        a2.z = fmaf(w6, bf2f(v6.z), a2.z); a2.w = fmaf(w6, bf2f(v6.w), a2.w);
        a3.x = fmaf(w7, bf2f(v7.x), a3.x); a3.y = fmaf(w7, bf2f(v7.y), a3.y);
        a3.z = fmaf(w7, bf2f(v7.z), a3.z); a3.w = fmaf(w7, bf2f(v7.w), a3.w);
    }
    for (; e < cnt; ++e) {
        unsigned int rc = el[e];
        int s = rc & 0xffff;
        float w = bf2f(rc >> 16);
        if (wrap_in && s >= NN) s -= NN;
        ushort4 v = ((const ushort4*)(hin + (size_t)s * ROWF))[lane];
        a0.x = fmaf(w, bf2f(v.x), a0.x); a0.y = fmaf(w, bf2f(v.y), a0.y);
        a0.z = fmaf(w, bf2f(v.z), a0.z); a0.w = fmaf(w, bf2f(v.w), a0.w);
    }
    float4 acc;
    acc.x = (a0.x + a1.x) + (a2.x + a3.x);
    acc.y = (a0.y + a1.y) + (a2.y + a3.y);
    acc.z = (a0.z + a1.z) + (a2.z + a3.z);
    acc.w = (a0.w + a1.w) + (a2.w + a3.w);
    float4 r;
    if (sub != nullptr) {
        int sn = wid;
        if (wrap_sub && sn >= NN) sn -= NN;
        ushort4 sv = ((const ushort4*)(sub + (size_t)sn * ROWF))[lane];
        r.x = scale * acc.x - bf2f(sv.x);
        r.y = scale * acc.y - bf2f(sv.y);
        r.z = scale * acc.z - bf2f(sv.z);
        r.w = scale * acc.w - bf2f(sv.w);
    } else {
        r = acc;
    }
    ushort4 o;
    o.x = f2bf(r.x); o.y = f2bf(r.y); o.z = f2bf(r.z); o.w = f2bf(r.w);
    ((ushort4*)(out + (size_t)wid * ROWF))[lane] = o;
}

// ---- Output matmul on MATRIX CORES: one wave per 16-row tile, no LDS. ----
__global__ __launch_bounds__(256) void out_mfma_kernel(
        const ushort* __restrict__ H, const ushort* __restrict__ Wp,
        const float* __restrict__ b, float* __restrict__ out) {
    int wave = (int)((blockIdx.x * blockDim.x + threadIdx.x) >> 6);
    int lane = threadIdx.x & 63;
    if (wave >= NROWS / 16) return;
    int rbase = wave * 16;
    int row = lane & 15;
    int kb  = lane >> 4;

    f32x4 acc[4];
    #pragma unroll
    for (int ct = 0; ct < 4; ++ct) {
        float bv = b[ct * 16 + row];
        acc[ct][0] = bv; acc[ct][1] = bv; acc[ct][2] = bv; acc[ct][3] = bv;
    }

    const ushort* ha = H + (size_t)(rbase + row) * CIN + kb * 8;
    #pragma unroll
    for (int a = 0; a < 7; ++a) {
        short8v af = *(const short8v*)(ha + (size_t)a * SEGB);
        const short8v* wp = (const short8v*)(Wp + (size_t)a * 2048);
        acc[0] = __builtin_amdgcn_mfma_f32_16x16x32_bf16(af, wp[0 * 64 + lane], acc[0], 0, 0, 0);
        acc[1] = __builtin_amdgcn_mfma_f32_16x16x32_bf16(af, wp[1 * 64 + lane], acc[1], 0, 0, 0);
        acc[2] = __builtin_amdgcn_mfma_f32_16x16x32_bf16(af, wp[2 * 64 + lane], acc[2], 0, 0, 0);
        acc[3] = __builtin_amdgcn_mfma_f32_16x16x32_bf16(af, wp[3 * 64 + lane], acc[3], 0, 0, 0);
    }

    // C/D: col = lane&15, row = (lane>>4)*4 + reg  [verified m89]
    int orow = rbase + kb * 4;
    #pragma unroll
    for (int ct = 0; ct < 4; ++ct) {
        int col = ct * 16 + row;
        #pragma unroll
        for (int r = 0; r < 4; ++r)
            out[(size_t)(orow + r) * COUT + col] = acc[ct][r];
    }
}

extern "C" void kernel_launch(void* const* d_in, const int* in_sizes, int n_in,
                              void* d_out, int out_size, void* d_ws, size_t ws_size,
                              hipStream_t stream) {
    const float* feat = (const float*)d_in[0];
    const float* ef   = (const float*)d_in[1];
    const float* W    = (const float*)d_in[2];
    const float* b    = (const float*)d_in[3];
    const int*   src  = (const int*)d_in[4];
    const int*   dst  = (const int*)d_in[5];
    float* out = (float*)d_out;

    // Workspace: [FEATB][X1B][X2B][X3B] bf16 (89.6 MB), [Wp], [counts], [edges 12.8 MB]
    ushort* FEATB = (ushort*)d_ws;
    ushort* X1B = FEATB + SEGB;
    ushort* X2B = X1B + (size_t)TWO_N * ROWF;
    ushort* X3B = X2B + (size_t)TWO_N * ROWF;
    ushort* Wp  = X3B + (size_t)TWO_N * ROWF;
    int* counts = (int*)(Wp + 7 * 4 * 64 * 8);
    unsigned int* edges = (unsigned int*)(counts + TWO_N + 64);

    feat2bf_kernel<<<(NN * ROWF / 4) / 256, 256, 0, stream>>>(feat, FEATB);
    packW_kernel<<<56, 256, 0, stream>>>(W, Wp);

    hipMemsetAsync(counts, 0, TWO_N * sizeof(int), stream);
    scatter_kernel<<<(NEDGE + 255) / 256, 256, 0, stream>>>(src, dst, ef, counts, edges);

    int spmm_grid = (TWO_N + 3) / 4;
    spmm_bf_kernel<<<spmm_grid, 256, 0, stream>>>(counts, edges,
                                                  FEATB, 1, nullptr, 0, 1.0f, X1B);
    spmm_bf_kernel<<<spmm_grid, 256, 0, stream>>>(counts, edges,
                                                  X1B, 0, FEATB, 1, 2.0f, X2B);
    spmm_bf_kernel<<<spmm_grid, 256, 0, stream>>>(counts, edges,
                                                  X2B, 0, X1B, 0, 2.0f, X3B);

    // Output projection: MFMA, 12500 waves = 3125 blocks x 4 waves
    out_mfma_kernel<<<3125, 256, 0, stream>>>(FEATB, Wp, b, out);
}